// Round 8
// baseline (4072.353 us; speedup 1.0000x reference)
//
#include <hip/hip_runtime.h>

#define NPTS 8192
#define NB 8
#define NS 2048
#define NK 32
// channel sizes
#define C0 67
#define C1 64
#define C2 64
#define C3 128
#define NTOT (NB*NS*NK)   // 524288 rows
#define NBLK 256
#define MAGIC 0xC0FFEE01u

// ---- DPP wave64 reduce helpers (VALU-speed cross-lane; result in lane 63) --
template <int CTRL, int ROWM>
__device__ __forceinline__ float dpp_fmax_step(float x) {
  int yi = __builtin_amdgcn_update_dpp(__float_as_int(x), __float_as_int(x),
                                       CTRL, ROWM, 0xf, false);
  return fmaxf(x, __int_as_float(yi));
}
template <int CTRL, int ROWM>
__device__ __forceinline__ unsigned dpp_umin_step(unsigned x) {
  unsigned y = (unsigned)__builtin_amdgcn_update_dpp((int)x, (int)x,
                                                     CTRL, ROWM, 0xf, false);
  return (y < x) ? y : x;
}
__device__ __forceinline__ float wave_max_f32(float v) {
  v = dpp_fmax_step<0x111, 0xf>(v);
  v = dpp_fmax_step<0x112, 0xf>(v);
  v = dpp_fmax_step<0x114, 0xf>(v);
  v = dpp_fmax_step<0x118, 0xf>(v);
  v = dpp_fmax_step<0x142, 0xa>(v);
  v = dpp_fmax_step<0x143, 0xc>(v);
  return v;                           // lane 63 = wave max
}
__device__ __forceinline__ unsigned wave_min_u32(unsigned v) {
  v = dpp_umin_step<0x111, 0xf>(v);
  v = dpp_umin_step<0x112, 0xf>(v);
  v = dpp_umin_step<0x114, 0xf>(v);
  v = dpp_umin_step<0x118, 0xf>(v);
  v = dpp_umin_step<0x142, 0xa>(v);
  v = dpp_umin_step<0x143, 0xc>(v);
  return v;                           // lane 63 = wave min
}

// ---- software grid barrier (all 256 blocks co-resident: 1 block/CU) -------
__device__ __forceinline__ void gbar(unsigned* ctr, unsigned target) {
  __syncthreads();
  if (threadIdx.x == 0) {
    __threadfence();   // release prior writes to agent scope
    __hip_atomic_fetch_add(ctr, 1u, __ATOMIC_ACQ_REL, __HIP_MEMORY_SCOPE_AGENT);
    while (__hip_atomic_load(ctr, __ATOMIC_ACQUIRE, __HIP_MEMORY_SCOPE_AGENT) < target)
      __builtin_amdgcn_s_sleep(8);
    __threadfence();   // acquire: invalidate L1 so the block sees remote writes
  }
  __syncthreads();
}

// ---- LDS union: FPS phase view / MLP phase view (max ~120.1 KB) ------------
union SMem {
  struct {
    float sx[NPTS], sy[NPTS], sz[NPTS];
    float snx[NS], sny[NS], snz[NS];
    uint2 slotVN[2][4];
  } fps;
  struct {
    float w0t[C0*64];
    float w1t[64*64];
    float w2t[64*128];
    float feat[C0*32];
    float x0n[64*32];
    float x1n[64*32];
    int   s_idx[32];
    float s_c[3];
  } mlp;
};

// Gather helper: builds feat[j][r] tile (j=0..66 channel, r=0..31 row) in LDS.
#define GATHER_GROUP(gid_, b_)                                                   \
  do {                                                                           \
    if (tid < 32) s_idxp[tid] = idx[(size_t)(gid_)*NK + tid];                    \
    if (tid < 3)  s_cp[tid]   = newxyz[(size_t)(gid_)*3 + tid];                  \
    __syncthreads();                                                             \
    if (tid < 32) {                                                              \
      const float* p = &xyz[((size_t)(b_)*NPTS + s_idxp[tid])*3];                \
      feat[0*32+tid] = p[0] - s_cp[0];                                           \
      feat[1*32+tid] = p[1] - s_cp[1];                                           \
      feat[2*32+tid] = p[2] - s_cp[2];                                           \
    }                                                                            \
    {                                                                            \
      int r_ = tid & 31, cq_ = tid >> 5;                                         \
      const float* pr = &pts[((size_t)(b_)*NPTS + s_idxp[r_])*64 + cq_*8];       \
      float4 A_ = *(const float4*)pr;                                            \
      float4 B_ = *(const float4*)(pr + 4);                                      \
      feat[(3+cq_*8+0)*32 + r_] = A_.x;                                          \
      feat[(3+cq_*8+1)*32 + r_] = A_.y;                                          \
      feat[(3+cq_*8+2)*32 + r_] = A_.z;                                          \
      feat[(3+cq_*8+3)*32 + r_] = A_.w;                                          \
      feat[(3+cq_*8+4)*32 + r_] = B_.x;                                          \
      feat[(3+cq_*8+5)*32 + r_] = B_.y;                                          \
      feat[(3+cq_*8+6)*32 + r_] = B_.z;                                          \
      feat[(3+cq_*8+7)*32 + r_] = B_.w;                                          \
    }                                                                            \
    __syncthreads();                                                             \
  } while (0)

// ---------------------------------------------------------------------------
// ONE fused kernel (plain launch + software grid barrier):
// FPS -> BQ -> L0stats -> fin0 -> L1stats -> fin1 -> L2 -> fin2 -> pool.
// 256 blocks x 256 threads, 1 block/CU (LDS-bound), all co-resident.
// ---------------------------------------------------------------------------
__global__ __launch_bounds__(256, 1) void k_all(
    const float* __restrict__ xyz, const float* __restrict__ pts,
    const float* __restrict__ w0, const float* __restrict__ g0, const float* __restrict__ be0,
    const float* __restrict__ w1, const float* __restrict__ g1, const float* __restrict__ be1,
    const float* __restrict__ w2, const float* __restrict__ g2, const float* __restrict__ be2,
    float* __restrict__ newxyz, float* __restrict__ pooled,
    float* __restrict__ pp, int* __restrict__ idx,
    float* __restrict__ part, float* __restrict__ statsF,
    float* __restrict__ maxb, float* __restrict__ minb,
    unsigned* __restrict__ bar) {
  __shared__ __align__(16) SMem sm;
  const int tid = threadIdx.x;
  unsigned* ctr  = bar;      // cumulative arrival counter
  unsigned* flag = bar + 16; // init-done flag

  // ---- barrier-state init handshake (ws is poisoned 0xAA each launch) ----
  if (blockIdx.x == 0 && tid == 0) {
    __hip_atomic_store(ctr, 0u, __ATOMIC_RELAXED, __HIP_MEMORY_SCOPE_AGENT);
    __hip_atomic_store(flag, MAGIC, __ATOMIC_RELEASE, __HIP_MEMORY_SCOPE_AGENT);
  }
  if (tid == 0) {
    while (__hip_atomic_load(flag, __ATOMIC_ACQUIRE, __HIP_MEMORY_SCOPE_AGENT) != MAGIC)
      __builtin_amdgcn_s_sleep(8);
  }
  __syncthreads();

  // ===== P0: FPS (blocks 0..7, one per batch; identical math to R6) =====
  if (blockIdx.x < NB) {
    const int b = blockIdx.x;
    const int wv = tid >> 6, lane = tid & 63;
    const float* Xb = xyz + (size_t)b * NPTS * 3;
    float px[32], py[32], pz[32], mind[32];
#pragma unroll
    for (int k = 0; k < 32; k++) {
      int n = (k << 8) | tid;
      float x = Xb[n*3+0], y = Xb[n*3+1], z = Xb[n*3+2];
      px[k]=x; py[k]=y; pz[k]=z;
      sm.fps.sx[n]=x; sm.fps.sy[n]=y; sm.fps.sz[n]=z;
      pp[b*NPTS + n] = __fadd_rn(__fadd_rn(__fmul_rn(x,x), __fmul_rn(y,y)), __fmul_rn(z,z));
      mind[k] = 1e10f;
    }
    __syncthreads();
    float lx = sm.fps.sx[0], ly = sm.fps.sy[0], lz = sm.fps.sz[0];
    if (tid == 0) { sm.fps.snx[0]=lx; sm.fps.sny[0]=ly; sm.fps.snz[0]=lz; }
    for (int s = 1; s < NS; s++) {
      float m32[32];
#pragma unroll
      for (int k = 0; k < 32; k++) {
        float dx = __fsub_rn(px[k], lx);
        float dy = __fsub_rn(py[k], ly);
        float dz = __fsub_rn(pz[k], lz);
        float d = __fadd_rn(__fadd_rn(__fmul_rn(dx,dx), __fmul_rn(dy,dy)), __fmul_rn(dz,dz));
        float m = fminf(mind[k], d);
        mind[k] = m;
        m32[k] = m;
      }
#pragma unroll
      for (int st = 16; st >= 1; st >>= 1)
#pragma unroll
        for (int k = 0; k < st; k++) m32[k] = fmaxf(m32[k], m32[k + st]);
      float v = m32[0];
      float vr = wave_max_f32(v);
      float wmax = __int_as_float(__builtin_amdgcn_readlane(__float_as_int(vr), 63));
      int kk = 31;
#pragma unroll
      for (int k = 30; k >= 0; k--) kk = (mind[k] == v) ? k : kk;
      unsigned ncand = (v == wmax) ? (unsigned)((kk << 8) | tid) : 0xffffffffu;
      unsigned nr = wave_min_u32(ncand);
      int buf = s & 1;
      if (lane == 63) sm.fps.slotVN[buf][wv] = make_uint2(__float_as_uint(vr), nr);
      __syncthreads();
      uint4 s01 = *(const uint4*)&sm.fps.slotVN[buf][0];
      uint4 s23 = *(const uint4*)&sm.fps.slotVN[buf][2];
      unsigned bx = s01.x, by = s01.y;
      if (s01.z > bx || (s01.z == bx && s01.w < by)) { bx = s01.z; by = s01.w; }
      if (s23.x > bx || (s23.x == bx && s23.y < by)) { bx = s23.x; by = s23.y; }
      if (s23.z > bx || (s23.z == bx && s23.w < by)) { bx = s23.z; by = s23.w; }
      int n = (int)by;
      lx = sm.fps.sx[n]; ly = sm.fps.sy[n]; lz = sm.fps.sz[n];
      if (tid == 0) { sm.fps.snx[s]=lx; sm.fps.sny[s]=ly; sm.fps.snz[s]=lz; }
    }
    __syncthreads();
    {
      float* o = newxyz + (size_t)b*NS*3;
      for (int t = tid; t < NS; t += 256) {
        o[t*3+0] = sm.fps.snx[t]; o[t*3+1] = sm.fps.sny[t]; o[t*3+2] = sm.fps.snz[t];
      }
    }
  }
  gbar(ctr, NBLK*1);

  // ===== P1: ball query — 64 centroids per block (16 per wave) =====
  {
    const int lane = tid & 63, wvl = tid >> 6;
    for (int i = 0; i < 16; i++) {
      int wvg = blockIdx.x * 64 + wvl * 16 + i;   // 0..16383
      int b = wvg >> 11;
      const float* c3 = newxyz + (size_t)wvg * 3;
      float cx = c3[0], cy = c3[1], cz = c3[2];
      float qq = __fadd_rn(__fadd_rn(__fmul_rn(cx,cx), __fmul_rn(cy,cy)), __fmul_rn(cz,cz));
      const float* Xb = xyz + (size_t)b * NPTS * 3;
      const float* Pb = pp + b * NPTS;
      int* out = idx + (size_t)wvg * NK;
      int cnt = 0, first = 0;
      for (int j0 = 0; j0 < NPTS; j0 += 64) {
        int n = j0 + lane;
        float x = Xb[n*3+0], y = Xb[n*3+1], z = Xb[n*3+2];
        float dot = __fadd_rn(__fadd_rn(__fmul_rn(cx,x), __fmul_rn(cy,y)), __fmul_rn(cz,z));
        float d2 = __fsub_rn(__fadd_rn(qq, Pb[n]), __fmul_rn(2.0f, dot));
        bool in = (d2 <= 0.0625f);
        unsigned long long bal = __ballot(in);
        if (cnt == 0 && bal) first = j0 + (int)__builtin_ctzll(bal);
        int c = (int)__popcll(bal);
        if (in) {
          int pos = cnt + (int)__popcll(bal & ((1ull << lane) - 1ull));
          if (pos < NK) out[pos] = n;
        }
        cnt += c;
        if (cnt >= NK) break;
      }
      if (cnt < NK) {
        if (lane >= cnt && lane < NK) out[lane] = first;
      }
    }
  }
  gbar(ctr, NBLK*2);

  // ===== P2: L0 stats — 64 groups per block =====
  {
    float* feat = sm.mlp.feat; float* w0t = sm.mlp.w0t;
    int* s_idxp = sm.mlp.s_idx; float* s_cp = sm.mlp.s_c;
    for (int t = tid; t < C0*64; t += 256) { int j = t >> 6, c = t & 63; w0t[t] = w0[c*C0 + j]; }
    int rt = tid & 7, ct = tid >> 3;
    float s0[2] = {0,0}, q0[2] = {0,0};
    for (int g = 0; g < 64; g++) {
      int gid = blockIdx.x * 64 + g;
      int b = gid >> 11;
      __syncthreads();
      GATHER_GROUP(gid, b);
      float acc[4][2] = {};
      for (int j = 0; j < C0; j++) {
        float4 av = *(const float4*)&feat[j*32 + rt*4];
        float2 wv = *(const float2*)&w0t[j*64 + ct*2];
        float aa[4] = {av.x, av.y, av.z, av.w};
#pragma unroll
        for (int r = 0; r < 4; r++) {
          acc[r][0] = fmaf(aa[r], wv.x, acc[r][0]);
          acc[r][1] = fmaf(aa[r], wv.y, acc[r][1]);
        }
      }
#pragma unroll
      for (int r = 0; r < 4; r++)
#pragma unroll
        for (int u = 0; u < 2; u++) { float x = acc[r][u]; s0[u] += x; q0[u] = fmaf(x, x, q0[u]); }
    }
#pragma unroll
    for (int off = 1; off < 8; off <<= 1) {
#pragma unroll
      for (int u = 0; u < 2; u++) { s0[u] += __shfl_xor(s0[u], off, 64); q0[u] += __shfl_xor(q0[u], off, 64); }
    }
    if (rt == 0) {
#pragma unroll
      for (int u = 0; u < 2; u++) {
        size_t o = ((size_t)blockIdx.x * 128 + ct*2 + u) * 2;
        part[o] = s0[u]; part[o+1] = q0[u];
      }
    }
  }
  gbar(ctr, NBLK*3);

  // ===== P3: fin0 (block 0) =====
  if (blockIdx.x == 0 && tid < 64) {
    float s = 0.f, q = 0.f;
    for (int k = 0; k < 256; k++) {
      s += part[((size_t)k * 128 + tid) * 2];
      q += part[((size_t)k * 128 + tid) * 2 + 1];
    }
    const float inv = 1.0f / (float)NTOT;
    float mean = s * inv;
    float var = q * inv - mean * mean;
    float a = g0[tid] / sqrtf(var + 1e-5f);
    float bb = be0[tid] - mean * a;
    statsF[(0*128 + tid)*2] = a; statsF[(0*128 + tid)*2 + 1] = bb;
  }
  gbar(ctr, NBLK*4);

  // ===== P4: L1 stats — 64 groups per block =====
  {
    float* feat = sm.mlp.feat; float* w0t = sm.mlp.w0t; float* w1t = sm.mlp.w1t;
    float* x0n = sm.mlp.x0n;
    int* s_idxp = sm.mlp.s_idx; float* s_cp = sm.mlp.s_c;
    for (int t = tid; t < 64*64; t += 256) { int j = t >> 6, c = t & 63; w1t[t] = w1[c*64 + j]; }
    int rt = tid & 7, ct = tid >> 3;
    float a0[2], b0v[2];
#pragma unroll
    for (int u = 0; u < 2; u++) {
      a0[u]  = statsF[(0*128 + ct*2 + u)*2];
      b0v[u] = statsF[(0*128 + ct*2 + u)*2 + 1];
    }
    float s1[2] = {0,0}, q1[2] = {0,0};
    for (int g = 0; g < 64; g++) {
      int gid = blockIdx.x * 64 + g;
      int b = gid >> 11;
      __syncthreads();
      GATHER_GROUP(gid, b);
      {
        float acc[4][2] = {};
        for (int j = 0; j < C0; j++) {
          float4 av = *(const float4*)&feat[j*32 + rt*4];
          float2 wv = *(const float2*)&w0t[j*64 + ct*2];
          float aa[4] = {av.x, av.y, av.z, av.w};
#pragma unroll
          for (int r = 0; r < 4; r++) {
            acc[r][0] = fmaf(aa[r], wv.x, acc[r][0]);
            acc[r][1] = fmaf(aa[r], wv.y, acc[r][1]);
          }
        }
#pragma unroll
        for (int u = 0; u < 2; u++) {
          float4 st;
          st.x = fmaxf(0.f, fmaf(acc[0][u], a0[u], b0v[u]));
          st.y = fmaxf(0.f, fmaf(acc[1][u], a0[u], b0v[u]));
          st.z = fmaxf(0.f, fmaf(acc[2][u], a0[u], b0v[u]));
          st.w = fmaxf(0.f, fmaf(acc[3][u], a0[u], b0v[u]));
          *(float4*)&x0n[(ct*2 + u)*32 + rt*4] = st;
        }
      }
      __syncthreads();
      {
        float acc[4][2] = {};
        for (int j = 0; j < 64; j++) {
          float4 av = *(const float4*)&x0n[j*32 + rt*4];
          float2 wv = *(const float2*)&w1t[j*64 + ct*2];
          float aa[4] = {av.x, av.y, av.z, av.w};
#pragma unroll
          for (int r = 0; r < 4; r++) {
            acc[r][0] = fmaf(aa[r], wv.x, acc[r][0]);
            acc[r][1] = fmaf(aa[r], wv.y, acc[r][1]);
          }
        }
#pragma unroll
        for (int r = 0; r < 4; r++)
#pragma unroll
          for (int u = 0; u < 2; u++) { float x = acc[r][u]; s1[u] += x; q1[u] = fmaf(x, x, q1[u]); }
      }
    }
#pragma unroll
    for (int off = 1; off < 8; off <<= 1) {
#pragma unroll
      for (int u = 0; u < 2; u++) { s1[u] += __shfl_xor(s1[u], off, 64); q1[u] += __shfl_xor(q1[u], off, 64); }
    }
    if (rt == 0) {
#pragma unroll
      for (int u = 0; u < 2; u++) {
        size_t o = ((size_t)blockIdx.x * 128 + ct*2 + u) * 2;
        part[o] = s1[u]; part[o+1] = q1[u];
      }
    }
  }
  gbar(ctr, NBLK*5);

  // ===== P5: fin1 (block 0) =====
  if (blockIdx.x == 0 && tid < 64) {
    float s = 0.f, q = 0.f;
    for (int k = 0; k < 256; k++) {
      s += part[((size_t)k * 128 + tid) * 2];
      q += part[((size_t)k * 128 + tid) * 2 + 1];
    }
    const float inv = 1.0f / (float)NTOT;
    float mean = s * inv;
    float var = q * inv - mean * mean;
    float a = g1[tid] / sqrtf(var + 1e-5f);
    float bb = be1[tid] - mean * a;
    statsF[(1*128 + tid)*2] = a; statsF[(1*128 + tid)*2 + 1] = bb;
  }
  gbar(ctr, NBLK*6);

  // ===== P6: L2 pass — 64 groups per block, stats2 + per-group max/min =====
  {
    float* feat = sm.mlp.feat; float* w0t = sm.mlp.w0t; float* w1t = sm.mlp.w1t;
    float* w2t = sm.mlp.w2t; float* x0n = sm.mlp.x0n; float* x1n = sm.mlp.x1n;
    int* s_idxp = sm.mlp.s_idx; float* s_cp = sm.mlp.s_c;
    for (int t = tid; t < 64*128; t += 256) { int j = t >> 7, c = t & 127; w2t[t] = w2[c*64 + j]; }
    int rt = tid & 7, ct = tid >> 3;
    float a0[2], b0v[2], a1[2], b1v[2];
#pragma unroll
    for (int u = 0; u < 2; u++) {
      a0[u]  = statsF[(0*128 + ct*2 + u)*2];
      b0v[u] = statsF[(0*128 + ct*2 + u)*2 + 1];
      a1[u]  = statsF[(1*128 + ct*2 + u)*2];
      b1v[u] = statsF[(1*128 + ct*2 + u)*2 + 1];
    }
    float s2[4] = {0,0,0,0}, q2[4] = {0,0,0,0};
    for (int g = 0; g < 64; g++) {
      int gid = blockIdx.x * 64 + g;
      int b = gid >> 11;
      __syncthreads();
      GATHER_GROUP(gid, b);
      {
        float acc[4][2] = {};
        for (int j = 0; j < C0; j++) {
          float4 av = *(const float4*)&feat[j*32 + rt*4];
          float2 wv = *(const float2*)&w0t[j*64 + ct*2];
          float aa[4] = {av.x, av.y, av.z, av.w};
#pragma unroll
          for (int r = 0; r < 4; r++) {
            acc[r][0] = fmaf(aa[r], wv.x, acc[r][0]);
            acc[r][1] = fmaf(aa[r], wv.y, acc[r][1]);
          }
        }
#pragma unroll
        for (int u = 0; u < 2; u++) {
          float4 st;
          st.x = fmaxf(0.f, fmaf(acc[0][u], a0[u], b0v[u]));
          st.y = fmaxf(0.f, fmaf(acc[1][u], a0[u], b0v[u]));
          st.z = fmaxf(0.f, fmaf(acc[2][u], a0[u], b0v[u]));
          st.w = fmaxf(0.f, fmaf(acc[3][u], a0[u], b0v[u]));
          *(float4*)&x0n[(ct*2 + u)*32 + rt*4] = st;
        }
      }
      __syncthreads();
      {
        float acc[4][2] = {};
        for (int j = 0; j < 64; j++) {
          float4 av = *(const float4*)&x0n[j*32 + rt*4];
          float2 wv = *(const float2*)&w1t[j*64 + ct*2];
          float aa[4] = {av.x, av.y, av.z, av.w};
#pragma unroll
          for (int r = 0; r < 4; r++) {
            acc[r][0] = fmaf(aa[r], wv.x, acc[r][0]);
            acc[r][1] = fmaf(aa[r], wv.y, acc[r][1]);
          }
        }
#pragma unroll
        for (int u = 0; u < 2; u++) {
          float4 st;
          st.x = fmaxf(0.f, fmaf(acc[0][u], a1[u], b1v[u]));
          st.y = fmaxf(0.f, fmaf(acc[1][u], a1[u], b1v[u]));
          st.z = fmaxf(0.f, fmaf(acc[2][u], a1[u], b1v[u]));
          st.w = fmaxf(0.f, fmaf(acc[3][u], a1[u], b1v[u]));
          *(float4*)&x1n[(ct*2 + u)*32 + rt*4] = st;
        }
      }
      __syncthreads();
      {
        float acc[4][4] = {};
        for (int j = 0; j < 64; j++) {
          float4 av = *(const float4*)&x1n[j*32 + rt*4];
          float4 wvv = *(const float4*)&w2t[j*128 + ct*4];
          float aa[4] = {av.x, av.y, av.z, av.w};
          float ww[4] = {wvv.x, wvv.y, wvv.z, wvv.w};
#pragma unroll
        for (int r = 0; r < 4; r++)
#pragma unroll
          for (int u = 0; u < 4; u++) acc[r][u] = fmaf(aa[r], ww[u], acc[r][u]);
        }
        float mx[4], mn[4];
#pragma unroll
        for (int u = 0; u < 4; u++) {
          float x0 = acc[0][u], x1 = acc[1][u], x2 = acc[2][u], x3 = acc[3][u];
          s2[u] += ((x0 + x1) + (x2 + x3));
          q2[u] = fmaf(x0, x0, q2[u]); q2[u] = fmaf(x1, x1, q2[u]);
          q2[u] = fmaf(x2, x2, q2[u]); q2[u] = fmaf(x3, x3, q2[u]);
          mx[u] = fmaxf(fmaxf(x0, x1), fmaxf(x2, x3));
          mn[u] = fminf(fminf(x0, x1), fminf(x2, x3));
        }
#pragma unroll
        for (int off = 1; off < 8; off <<= 1) {
#pragma unroll
          for (int u = 0; u < 4; u++) {
            mx[u] = fmaxf(mx[u], __shfl_xor(mx[u], off, 64));
            mn[u] = fminf(mn[u], __shfl_xor(mn[u], off, 64));
          }
        }
        if (rt == 0) {
#pragma unroll
          for (int u = 0; u < 4; u++) {
            maxb[(size_t)gid*128 + ct*4 + u] = mx[u];
            minb[(size_t)gid*128 + ct*4 + u] = mn[u];
          }
        }
      }
    }
#pragma unroll
    for (int off = 1; off < 8; off <<= 1) {
#pragma unroll
      for (int u = 0; u < 4; u++) { s2[u] += __shfl_xor(s2[u], off, 64); q2[u] += __shfl_xor(q2[u], off, 64); }
    }
    if (rt == 0) {
#pragma unroll
      for (int u = 0; u < 4; u++) {
        size_t o = ((size_t)blockIdx.x * 128 + ct*4 + u) * 2;
        part[o] = s2[u]; part[o+1] = q2[u];
      }
    }
  }
  gbar(ctr, NBLK*7);

  // ===== P7: fin2 (block 0, 128 channels) =====
  if (blockIdx.x == 0 && tid < 128) {
    float s = 0.f, q = 0.f;
    for (int k = 0; k < 256; k++) {
      s += part[((size_t)k * 128 + tid) * 2];
      q += part[((size_t)k * 128 + tid) * 2 + 1];
    }
    const float inv = 1.0f / (float)NTOT;
    float mean = s * inv;
    float var = q * inv - mean * mean;
    float a = g2[tid] / sqrtf(var + 1e-5f);
    float bb = be2[tid] - mean * a;
    statsF[(2*128 + tid)*2] = a; statsF[(2*128 + tid)*2 + 1] = bb;
  }
  gbar(ctr, NBLK*8);

  // ===== P8: pool epilogue — 8192 elements per block =====
  {
    for (int k = 0; k < 32; k++) {
      int t = blockIdx.x * 8192 + k*256 + tid;
      int c = t & 127;
      float a  = statsF[(2*128 + c)*2];
      float bb = statsF[(2*128 + c)*2 + 1];
      float X = (a >= 0.f) ? maxb[t] : minb[t];
      pooled[t] = fmaxf(0.f, fmaf(a, X, bb));
    }
  }
}

// ---------------------------------------------------------------------------
extern "C" void kernel_launch(void* const* d_in, const int* in_sizes, int n_in,
                              void* d_out, int out_size, void* d_ws, size_t ws_size,
                              hipStream_t stream) {
  (void)in_sizes; (void)n_in; (void)out_size; (void)ws_size;
  const float* xyz = (const float*)d_in[0];
  const float* pts = (const float*)d_in[1];
  const float* w0  = (const float*)d_in[2];
  const float* g0  = (const float*)d_in[4];
  const float* be0 = (const float*)d_in[5];
  const float* w1  = (const float*)d_in[6];
  const float* g1  = (const float*)d_in[8];
  const float* be1 = (const float*)d_in[9];
  const float* w2  = (const float*)d_in[10];
  const float* g2  = (const float*)d_in[12];
  const float* be2 = (const float*)d_in[13];

  float* out = (float*)d_out;
  float* newxyz = out;                    // [B,S,3]
  float* pooled = out + (size_t)NB*NS*3;  // [B,S,128]

  float* ws = (float*)d_ws;
  float* pp     = ws;                                 // 65536
  int*   idx    = (int*)(ws + 65536);                 // 524288 ints
  float* part   = ws + 65536 + 524288;                // 65536 used (131072 reserved)
  float* statsF = part + 131072;                      // 768
  float* maxb   = statsF + 768;                       // 2097152
  float* minb   = maxb + 2097152;                     // 2097152
  unsigned* bar = (unsigned*)(minb + 2097152);        // 32 u32 barrier slots

  k_all<<<256, 256, 0, stream>>>(xyz, pts, w0, g0, be0, w1, g1, be1,
                                 w2, g2, be2, newxyz, pooled,
                                 pp, idx, part, statsF, maxb, minb, bar);
}

// Round 10
// 3498.432 us; speedup vs baseline: 1.1641x; 1.1641x over previous
//
#include <hip/hip_runtime.h>

#define NPTS 8192
#define NB 8
#define NS 2048
#define NK 32
// channel sizes
#define C0 67
#define C1 64
#define C2 64
#define C3 128
#define NTOT (NB*NS*NK)   // 524288 rows
#define NCONS 248
#define MAGIC 0xC0FFEE01u

// ---- DPP wave64 reduce helpers (VALU-speed cross-lane; result in lane 63) --
template <int CTRL, int ROWM>
__device__ __forceinline__ float dpp_fmax_step(float x) {
  int yi = __builtin_amdgcn_update_dpp(__float_as_int(x), __float_as_int(x),
                                       CTRL, ROWM, 0xf, false);
  return fmaxf(x, __int_as_float(yi));
}
template <int CTRL, int ROWM>
__device__ __forceinline__ unsigned dpp_umin_step(unsigned x) {
  unsigned y = (unsigned)__builtin_amdgcn_update_dpp((int)x, (int)x,
                                                     CTRL, ROWM, 0xf, false);
  return (y < x) ? y : x;
}
__device__ __forceinline__ float wave_max_f32(float v) {
  v = dpp_fmax_step<0x111, 0xf>(v);
  v = dpp_fmax_step<0x112, 0xf>(v);
  v = dpp_fmax_step<0x114, 0xf>(v);
  v = dpp_fmax_step<0x118, 0xf>(v);
  v = dpp_fmax_step<0x142, 0xa>(v);
  v = dpp_fmax_step<0x143, 0xc>(v);
  return v;
}
__device__ __forceinline__ unsigned wave_min_u32(unsigned v) {
  v = dpp_umin_step<0x111, 0xf>(v);
  v = dpp_umin_step<0x112, 0xf>(v);
  v = dpp_umin_step<0x114, 0xf>(v);
  v = dpp_umin_step<0x118, 0xf>(v);
  v = dpp_umin_step<0x142, 0xa>(v);
  v = dpp_umin_step<0x143, 0xc>(v);
  return v;
}

// ---- LDS union: FPS producer view / BQ+L0 consumer view --------------------
union SMem1 {
  struct {
    float sx[NPTS], sy[NPTS], sz[NPTS];
    float snx[NS], sny[NS], snz[NS];
    uint2 slotVN[2][4];
  } fps;
  struct {
    float w0t[C0*64];
    float feat[C0*32];
    int   bq[4][32];
    int   bqc[4];
    int   s_idx[32];
    float s_c[3];
  } con;
};

// ---------------------------------------------------------------------------
// Stage 1: FPS (blocks 0..7) producing centroids; consumers (blocks 8..255)
// do ball-query + L0 GEMM stats pipelined against per-batch FPS progress.
// Exact np-f32 semantics preserved everywhere (rn ops, no fma in decisions).
// ---------------------------------------------------------------------------
__global__ __launch_bounds__(256, 1) void k_stage1(
    const float* __restrict__ xyz, const float* __restrict__ pts,
    const float* __restrict__ w0,
    float* __restrict__ newxyz, float* __restrict__ pp, int* __restrict__ idx,
    float* __restrict__ part, unsigned* __restrict__ prog,
    unsigned* __restrict__ flag) {
  __shared__ __align__(16) SMem1 sm;
  const int tid = threadIdx.x;

  // init handshake: block 0 zeroes progress then releases MAGIC flag
  if (blockIdx.x == 0 && tid == 0) {
    for (int i = 0; i < NB; i++)
      __hip_atomic_store(&prog[i], 0u, __ATOMIC_RELAXED, __HIP_MEMORY_SCOPE_AGENT);
    __threadfence();
    __hip_atomic_store(flag, MAGIC, __ATOMIC_RELEASE, __HIP_MEMORY_SCOPE_AGENT);
  }
  if (tid == 0) {
    while (__hip_atomic_load(flag, __ATOMIC_ACQUIRE, __HIP_MEMORY_SCOPE_AGENT) != MAGIC)
      __builtin_amdgcn_s_sleep(8);
  }
  __syncthreads();

  if (blockIdx.x < NB) {
    // ===================== PRODUCER: FPS for batch b =====================
    const int b = blockIdx.x;
    const int wv = tid >> 6, lane = tid & 63;
    const float* Xb = xyz + (size_t)b * NPTS * 3;
    float px[32], py[32], pz[32], mind[32];
#pragma unroll
    for (int k = 0; k < 32; k++) {
      int n = (k << 8) | tid;
      float x = Xb[n*3+0], y = Xb[n*3+1], z = Xb[n*3+2];
      px[k]=x; py[k]=y; pz[k]=z;
      sm.fps.sx[n]=x; sm.fps.sy[n]=y; sm.fps.sz[n]=z;
      pp[b*NPTS + n] = __fadd_rn(__fadd_rn(__fmul_rn(x,x), __fmul_rn(y,y)), __fmul_rn(z,z));
      mind[k] = 1e10f;
    }
    __syncthreads();
    float lx = sm.fps.sx[0], ly = sm.fps.sy[0], lz = sm.fps.sz[0];
    if (tid == 0) { sm.fps.snx[0]=lx; sm.fps.sny[0]=ly; sm.fps.snz[0]=lz; }
    for (int s = 1; s < NS; s++) {
      float m32[32];
#pragma unroll
      for (int k = 0; k < 32; k++) {
        float dx = __fsub_rn(px[k], lx);
        float dy = __fsub_rn(py[k], ly);
        float dz = __fsub_rn(pz[k], lz);
        float d = __fadd_rn(__fadd_rn(__fmul_rn(dx,dx), __fmul_rn(dy,dy)), __fmul_rn(dz,dz));
        float m = fminf(mind[k], d);
        mind[k] = m;
        m32[k] = m;
      }
#pragma unroll
      for (int st = 16; st >= 1; st >>= 1)
#pragma unroll
        for (int k = 0; k < st; k++) m32[k] = fmaxf(m32[k], m32[k + st]);
      float v = m32[0];
      float vr = wave_max_f32(v);
      float wmax = __int_as_float(__builtin_amdgcn_readlane(__float_as_int(vr), 63));
      int kk = 31;
#pragma unroll
      for (int k = 30; k >= 0; k--) kk = (mind[k] == v) ? k : kk;
      unsigned ncand = (v == wmax) ? (unsigned)((kk << 8) | tid) : 0xffffffffu;
      unsigned nr = wave_min_u32(ncand);
      int buf = s & 1;
      if (lane == 63) sm.fps.slotVN[buf][wv] = make_uint2(__float_as_uint(vr), nr);
      __syncthreads();
      uint4 s01 = *(const uint4*)&sm.fps.slotVN[buf][0];
      uint4 s23 = *(const uint4*)&sm.fps.slotVN[buf][2];
      unsigned bx = s01.x, by = s01.y;
      if (s01.z > bx || (s01.z == bx && s01.w < by)) { bx = s01.z; by = s01.w; }
      if (s23.x > bx || (s23.x == bx && s23.y < by)) { bx = s23.x; by = s23.y; }
      if (s23.z > bx || (s23.z == bx && s23.w < by)) { bx = s23.z; by = s23.w; }
      int n = (int)by;
      lx = sm.fps.sx[n]; ly = sm.fps.sy[n]; lz = sm.fps.sz[n];
      if (tid == 0) { sm.fps.snx[s]=lx; sm.fps.sny[s]=ly; sm.fps.snz[s]=lz; }
      // flush + publish every 64 steps
      if ((s & 63) == 63) {
        __syncthreads();   // snx[..s] visible to flush threads
        int cs = s - 63;
        if (tid < 192) {
          int e = cs + tid / 3, comp = tid - (tid / 3) * 3;
          float vvv = (comp == 0) ? sm.fps.snx[e] : ((comp == 1) ? sm.fps.sny[e] : sm.fps.snz[e]);
          newxyz[((size_t)b*NS + cs)*3 + tid] = vvv;
        }
        __syncthreads();   // drains vmcnt: flush stores complete
        if (tid == 0) {
          __threadfence();
          __hip_atomic_store(&prog[b], (unsigned)(s + 1), __ATOMIC_RELEASE, __HIP_MEMORY_SCOPE_AGENT);
        }
      }
    }
  } else {
    // ===================== CONSUMER: BQ + L0 stats =====================
    const int cb = blockIdx.x - NB;          // 0..247
    const int wv = tid >> 6, lane = tid & 63;
    float* w0t = sm.con.w0t;
    float* feat = sm.con.feat;
    for (int t = tid; t < C0*64; t += 256) { int j = t >> 6, c = t & 63; w0t[t] = w0[c*C0 + j]; }
    int rt = tid & 7, ct = tid >> 3;
    float s0[2] = {0,0}, q0[2] = {0,0};
    for (int it = 0; it <= 66; it++) {
      int e = cb + NCONS * it;               // enumeration id (batch-minor)
      if (e >= NB*NS) break;
      int s = e >> 3, b = e & 7;             // earliest-available ordering
      size_t row = (size_t)b * NS + s;       // STORAGE row = b*NS + s  (R9 bug fix)
      if (tid == 0) {
        while ((int)__hip_atomic_load(&prog[b], __ATOMIC_ACQUIRE, __HIP_MEMORY_SCOPE_AGENT) <= s)
          __builtin_amdgcn_s_sleep(32);
        __threadfence();
      }
      __syncthreads();
      // ---- wave-parallel ball query: wave wv scans [wv*2048, +2048) ----
      const float* c3 = newxyz + row * 3;
      float cx = c3[0], cy = c3[1], cz = c3[2];
      float qq = __fadd_rn(__fadd_rn(__fmul_rn(cx,cx), __fmul_rn(cy,cy)), __fmul_rn(cz,cz));
      const float* Xb = xyz + (size_t)b * NPTS * 3;
      const float* Pb = pp + b * NPTS;
      int cnt = 0;
      int base = wv << 11;
      for (int j0 = base; j0 < base + 2048; j0 += 64) {
        int n = j0 + lane;
        float x = Xb[n*3+0], y = Xb[n*3+1], z = Xb[n*3+2];
        float dot = __fadd_rn(__fadd_rn(__fmul_rn(cx,x), __fmul_rn(cy,y)), __fmul_rn(cz,z));
        float d2 = __fsub_rn(__fadd_rn(qq, Pb[n]), __fmul_rn(2.0f, dot));
        bool in = (d2 <= 0.0625f);
        unsigned long long bal = __ballot(in);
        if (in) {
          int pos = cnt + (int)__popcll(bal & ((1ull << lane) - 1ull));
          if (pos < NK) sm.con.bq[wv][pos] = n;
        }
        cnt += (int)__popcll(bal);
        if (cnt >= NK) break;
      }
      if (lane == 0) sm.con.bqc[wv] = (cnt < NK) ? cnt : NK;
      __syncthreads();
      // ---- ordered merge of 4 per-wave lists -> first NK by index ----
      if (tid < NK) {
        int l0 = sm.con.bqc[0], l1 = sm.con.bqc[1], l2 = sm.con.bqc[2], l3 = sm.con.bqc[3];
        int t1 = l0 + l1, t2 = t1 + l2, t3 = t2 + l3;
        int j = tid, v;
        if (j < l0)      v = sm.con.bq[0][j];
        else if (j < t1) v = sm.con.bq[1][j - l0];
        else if (j < t2) v = sm.con.bq[2][j - t1];
        else if (j < t3) v = sm.con.bq[3][j - t2];
        else {
          v = (l0 > 0) ? sm.con.bq[0][0] : (l1 > 0) ? sm.con.bq[1][0]
            : (l2 > 0) ? sm.con.bq[2][0] : (l3 > 0) ? sm.con.bq[3][0] : 0;
        }
        sm.con.s_idx[j] = v;
        idx[row * NK + j] = v;
      }
      if (tid >= 32 && tid < 35) sm.con.s_c[tid - 32] = c3[tid - 32];
      __syncthreads();
      // ---- gather feat tile ----
      if (tid < 32) {
        const float* p = &xyz[((size_t)b*NPTS + sm.con.s_idx[tid])*3];
        feat[0*32+tid] = p[0] - sm.con.s_c[0];
        feat[1*32+tid] = p[1] - sm.con.s_c[1];
        feat[2*32+tid] = p[2] - sm.con.s_c[2];
      }
      {
        int r_ = tid & 31, cq_ = tid >> 5;
        const float* pr = &pts[((size_t)b*NPTS + sm.con.s_idx[r_])*64 + cq_*8];
        float4 A_ = *(const float4*)pr;
        float4 B_ = *(const float4*)(pr + 4);
        feat[(3+cq_*8+0)*32 + r_] = A_.x;
        feat[(3+cq_*8+1)*32 + r_] = A_.y;
        feat[(3+cq_*8+2)*32 + r_] = A_.z;
        feat[(3+cq_*8+3)*32 + r_] = A_.w;
        feat[(3+cq_*8+4)*32 + r_] = B_.x;
        feat[(3+cq_*8+5)*32 + r_] = B_.y;
        feat[(3+cq_*8+6)*32 + r_] = B_.z;
        feat[(3+cq_*8+7)*32 + r_] = B_.w;
      }
      __syncthreads();
      // ---- L0 GEMM (4 rows x 2 cols per thread) + stats ----
      float acc[4][2] = {};
      for (int j = 0; j < C0; j++) {
        float4 av = *(const float4*)&feat[j*32 + rt*4];
        float2 wvv = *(const float2*)&w0t[j*64 + ct*2];
        float aa[4] = {av.x, av.y, av.z, av.w};
#pragma unroll
        for (int r = 0; r < 4; r++) {
          acc[r][0] = fmaf(aa[r], wvv.x, acc[r][0]);
          acc[r][1] = fmaf(aa[r], wvv.y, acc[r][1]);
        }
      }
#pragma unroll
      for (int r = 0; r < 4; r++)
#pragma unroll
        for (int u = 0; u < 2; u++) { float x = acc[r][u]; s0[u] += x; q0[u] = fmaf(x, x, q0[u]); }
      __syncthreads();   // protect feat/bq reuse next iteration
    }
#pragma unroll
    for (int off = 1; off < 8; off <<= 1) {
#pragma unroll
      for (int u = 0; u < 2; u++) { s0[u] += __shfl_xor(s0[u], off, 64); q0[u] += __shfl_xor(q0[u], off, 64); }
    }
    if (rt == 0) {
#pragma unroll
      for (int u = 0; u < 2; u++) {
        size_t o = ((size_t)cb * 128 + ct*2 + u) * 2;
        part[o] = s0[u]; part[o+1] = q0[u];
      }
    }
  }
}

// ---------------------------------------------------------------------------
// Gather helper for L1/L2 passes (reads idx from global).
// ---------------------------------------------------------------------------
#define GATHER_GROUP(gid_, b_)                                                   \
  do {                                                                           \
    if (tid < 32) s_idx[tid] = idx[(size_t)(gid_)*NK + tid];                     \
    if (tid < 3)  s_c[tid]   = newxyz[(size_t)(gid_)*3 + tid];                   \
    __syncthreads();                                                             \
    if (tid < 32) {                                                              \
      const float* p = &xyz[((size_t)(b_)*NPTS + s_idx[tid])*3];                 \
      feat[0*32+tid] = p[0] - s_c[0];                                            \
      feat[1*32+tid] = p[1] - s_c[1];                                            \
      feat[2*32+tid] = p[2] - s_c[2];                                            \
    }                                                                            \
    {                                                                            \
      int r_ = tid & 31, cq_ = tid >> 5;                                         \
      const float* pr = &pts[((size_t)(b_)*NPTS + s_idx[r_])*64 + cq_*8];        \
      float4 A_ = *(const float4*)pr;                                            \
      float4 B_ = *(const float4*)(pr + 4);                                      \
      feat[(3+cq_*8+0)*32 + r_] = A_.x;                                          \
      feat[(3+cq_*8+1)*32 + r_] = A_.y;                                          \
      feat[(3+cq_*8+2)*32 + r_] = A_.z;                                          \
      feat[(3+cq_*8+3)*32 + r_] = A_.w;                                          \
      feat[(3+cq_*8+4)*32 + r_] = B_.x;                                          \
      feat[(3+cq_*8+5)*32 + r_] = B_.y;                                          \
      feat[(3+cq_*8+6)*32 + r_] = B_.z;                                          \
      feat[(3+cq_*8+7)*32 + r_] = B_.w;                                          \
    }                                                                            \
    __syncthreads();                                                             \
  } while (0)

// ---------------------------------------------------------------------------
// Pass B: recompute L0, apply BN0+ReLU, L1 GEMM, accumulate stats1.
// ---------------------------------------------------------------------------
__global__ __launch_bounds__(256) void k_l1stats(const float* __restrict__ xyz,
                                                 const float* __restrict__ pts,
                                                 const float* __restrict__ newxyz,
                                                 const int* __restrict__ idx,
                                                 const float* __restrict__ w0,
                                                 const float* __restrict__ w1,
                                                 const float* __restrict__ statsF,
                                                 float* __restrict__ partials) {
  __shared__ __align__(16) float w0t[C0*64];
  __shared__ __align__(16) float w1t[64*64];
  __shared__ __align__(16) float feat[C0*32];
  __shared__ __align__(16) float x0n[64*32];
  __shared__ int s_idx[32];
  __shared__ float s_c[3];
  int tid = threadIdx.x;
  for (int t = tid; t < C0*64; t += 256) { int j = t >> 6, c = t & 63; w0t[t] = w0[c*C0 + j]; }
  for (int t = tid; t < 64*64; t += 256) { int j = t >> 6, c = t & 63; w1t[t] = w1[c*64 + j]; }
  int rt = tid & 7, ct = tid >> 3;
  float a0[2], b0v[2];
#pragma unroll
  for (int u = 0; u < 2; u++) {
    a0[u]  = statsF[(0*128 + ct*2 + u)*2];
    b0v[u] = statsF[(0*128 + ct*2 + u)*2 + 1];
  }
  float s1[2] = {0,0}, q1[2] = {0,0};
  for (int g = 0; g < 32; g++) {
    int gid = blockIdx.x * 32 + g;
    int b = gid >> 11;
    __syncthreads();
    GATHER_GROUP(gid, b);
    {
      float acc[4][2] = {};
      for (int j = 0; j < C0; j++) {
        float4 av = *(const float4*)&feat[j*32 + rt*4];
        float2 wv = *(const float2*)&w0t[j*64 + ct*2];
        float aa[4] = {av.x, av.y, av.z, av.w};
#pragma unroll
        for (int r = 0; r < 4; r++) {
          acc[r][0] = fmaf(aa[r], wv.x, acc[r][0]);
          acc[r][1] = fmaf(aa[r], wv.y, acc[r][1]);
        }
      }
#pragma unroll
      for (int u = 0; u < 2; u++) {
        float4 st;
        st.x = fmaxf(0.f, fmaf(acc[0][u], a0[u], b0v[u]));
        st.y = fmaxf(0.f, fmaf(acc[1][u], a0[u], b0v[u]));
        st.z = fmaxf(0.f, fmaf(acc[2][u], a0[u], b0v[u]));
        st.w = fmaxf(0.f, fmaf(acc[3][u], a0[u], b0v[u]));
        *(float4*)&x0n[(ct*2 + u)*32 + rt*4] = st;
      }
    }
    __syncthreads();
    {
      float acc[4][2] = {};
      for (int j = 0; j < 64; j++) {
        float4 av = *(const float4*)&x0n[j*32 + rt*4];
        float2 wv = *(const float2*)&w1t[j*64 + ct*2];
        float aa[4] = {av.x, av.y, av.z, av.w};
#pragma unroll
        for (int r = 0; r < 4; r++) {
          acc[r][0] = fmaf(aa[r], wv.x, acc[r][0]);
          acc[r][1] = fmaf(aa[r], wv.y, acc[r][1]);
        }
      }
#pragma unroll
      for (int r = 0; r < 4; r++)
#pragma unroll
        for (int u = 0; u < 2; u++) { float x = acc[r][u]; s1[u] += x; q1[u] = fmaf(x, x, q1[u]); }
    }
  }
#pragma unroll
  for (int off = 1; off < 8; off <<= 1) {
#pragma unroll
    for (int u = 0; u < 2; u++) { s1[u] += __shfl_xor(s1[u], off, 64); q1[u] += __shfl_xor(q1[u], off, 64); }
  }
  if (rt == 0) {
#pragma unroll
    for (int u = 0; u < 2; u++) {
      size_t o = ((size_t)blockIdx.x * 128 + ct*2 + u) * 2;
      partials[o] = s1[u]; partials[o+1] = q1[u];
    }
  }
}

// ---------------------------------------------------------------------------
// Pass C: recompute L0,L1 (BN+ReLU), L2 pre-BN: stats2 + per-group max/min.
// ---------------------------------------------------------------------------
__global__ __launch_bounds__(256) void k_l2(const float* __restrict__ xyz,
                                            const float* __restrict__ pts,
                                            const float* __restrict__ newxyz,
                                            const int* __restrict__ idx,
                                            const float* __restrict__ w0,
                                            const float* __restrict__ w1,
                                            const float* __restrict__ w2,
                                            const float* __restrict__ statsF,
                                            float* __restrict__ partials,
                                            float* __restrict__ maxb,
                                            float* __restrict__ minb) {
  __shared__ __align__(16) float w0t[C0*64];
  __shared__ __align__(16) float w1t[64*64];
  __shared__ __align__(16) float w2t[64*128];
  __shared__ __align__(16) float feat[C0*32];
  __shared__ __align__(16) float x0n[64*32];
  __shared__ __align__(16) float x1n[64*32];
  __shared__ int s_idx[32];
  __shared__ float s_c[3];
  int tid = threadIdx.x;
  for (int t = tid; t < C0*64; t += 256) { int j = t >> 6, c = t & 63; w0t[t] = w0[c*C0 + j]; }
  for (int t = tid; t < 64*64; t += 256) { int j = t >> 6, c = t & 63; w1t[t] = w1[c*64 + j]; }
  for (int t = tid; t < 64*128; t += 256) { int j = t >> 7, c = t & 127; w2t[t] = w2[c*64 + j]; }
  int rt = tid & 7, ct = tid >> 3;
  float a0[2], b0v[2], a1[2], b1v[2];
#pragma unroll
  for (int u = 0; u < 2; u++) {
    a0[u]  = statsF[(0*128 + ct*2 + u)*2];
    b0v[u] = statsF[(0*128 + ct*2 + u)*2 + 1];
    a1[u]  = statsF[(1*128 + ct*2 + u)*2];
    b1v[u] = statsF[(1*128 + ct*2 + u)*2 + 1];
  }
  float s2[4] = {0,0,0,0}, q2[4] = {0,0,0,0};
  for (int g = 0; g < 64; g++) {
    int gid = blockIdx.x * 64 + g;
    int b = gid >> 11;
    __syncthreads();
    GATHER_GROUP(gid, b);
    {
      float acc[4][2] = {};
      for (int j = 0; j < C0; j++) {
        float4 av = *(const float4*)&feat[j*32 + rt*4];
        float2 wv = *(const float2*)&w0t[j*64 + ct*2];
        float aa[4] = {av.x, av.y, av.z, av.w};
#pragma unroll
        for (int r = 0; r < 4; r++) {
          acc[r][0] = fmaf(aa[r], wv.x, acc[r][0]);
          acc[r][1] = fmaf(aa[r], wv.y, acc[r][1]);
        }
      }
#pragma unroll
      for (int u = 0; u < 2; u++) {
        float4 st;
        st.x = fmaxf(0.f, fmaf(acc[0][u], a0[u], b0v[u]));
        st.y = fmaxf(0.f, fmaf(acc[1][u], a0[u], b0v[u]));
        st.z = fmaxf(0.f, fmaf(acc[2][u], a0[u], b0v[u]));
        st.w = fmaxf(0.f, fmaf(acc[3][u], a0[u], b0v[u]));
        *(float4*)&x0n[(ct*2 + u)*32 + rt*4] = st;
      }
    }
    __syncthreads();
    {
      float acc[4][2] = {};
      for (int j = 0; j < 64; j++) {
        float4 av = *(const float4*)&x0n[j*32 + rt*4];
        float2 wv = *(const float2*)&w1t[j*64 + ct*2];
        float aa[4] = {av.x, av.y, av.z, av.w};
#pragma unroll
        for (int r = 0; r < 4; r++) {
          acc[r][0] = fmaf(aa[r], wv.x, acc[r][0]);
          acc[r][1] = fmaf(aa[r], wv.y, acc[r][1]);
        }
      }
#pragma unroll
      for (int u = 0; u < 2; u++) {
        float4 st;
        st.x = fmaxf(0.f, fmaf(acc[0][u], a1[u], b1v[u]));
        st.y = fmaxf(0.f, fmaf(acc[1][u], a1[u], b1v[u]));
        st.z = fmaxf(0.f, fmaf(acc[2][u], a1[u], b1v[u]));
        st.w = fmaxf(0.f, fmaf(acc[3][u], a1[u], b1v[u]));
        *(float4*)&x1n[(ct*2 + u)*32 + rt*4] = st;
      }
    }
    __syncthreads();
    {
      float acc[4][4] = {};
      for (int j = 0; j < 64; j++) {
        float4 av = *(const float4*)&x1n[j*32 + rt*4];
        float4 wvv = *(const float4*)&w2t[j*128 + ct*4];
        float aa[4] = {av.x, av.y, av.z, av.w};
        float ww[4] = {wvv.x, wvv.y, wvv.z, wvv.w};
#pragma unroll
      for (int r = 0; r < 4; r++)
#pragma unroll
        for (int u = 0; u < 4; u++) acc[r][u] = fmaf(aa[r], ww[u], acc[r][u]);
      }
      float mx[4], mn[4];
#pragma unroll
      for (int u = 0; u < 4; u++) {
        float x0 = acc[0][u], x1 = acc[1][u], x2 = acc[2][u], x3 = acc[3][u];
        s2[u] += ((x0 + x1) + (x2 + x3));
        q2[u] = fmaf(x0, x0, q2[u]); q2[u] = fmaf(x1, x1, q2[u]);
        q2[u] = fmaf(x2, x2, q2[u]); q2[u] = fmaf(x3, x3, q2[u]);
        mx[u] = fmaxf(fmaxf(x0, x1), fmaxf(x2, x3));
        mn[u] = fminf(fminf(x0, x1), fminf(x2, x3));
      }
#pragma unroll
      for (int off = 1; off < 8; off <<= 1) {
#pragma unroll
        for (int u = 0; u < 4; u++) {
          mx[u] = fmaxf(mx[u], __shfl_xor(mx[u], off, 64));
          mn[u] = fminf(mn[u], __shfl_xor(mn[u], off, 64));
        }
      }
      if (rt == 0) {
#pragma unroll
        for (int u = 0; u < 4; u++) {
          maxb[(size_t)gid*128 + ct*4 + u] = mx[u];
          minb[(size_t)gid*128 + ct*4 + u] = mn[u];
        }
      }
    }
  }
#pragma unroll
  for (int off = 1; off < 8; off <<= 1) {
#pragma unroll
    for (int u = 0; u < 4; u++) { s2[u] += __shfl_xor(s2[u], off, 64); q2[u] += __shfl_xor(q2[u], off, 64); }
  }
  if (rt == 0) {
#pragma unroll
    for (int u = 0; u < 4; u++) {
      size_t o = ((size_t)blockIdx.x * 128 + ct*4 + u) * 2;
      partials[o] = s2[u]; partials[o+1] = q2[u];
    }
  }
}

// ---------------------------------------------------------------------------
__global__ void k_fin(const float* __restrict__ partials, int nblk,
                      const float* __restrict__ g, const float* __restrict__ be,
                      float* __restrict__ statsF, int layer, int C) {
  int c = threadIdx.x;
  if (c >= C) return;
  float s = 0.f, q = 0.f;
  for (int k = 0; k < nblk; k++) {
    s += partials[((size_t)k * 128 + c) * 2];
    q += partials[((size_t)k * 128 + c) * 2 + 1];
  }
  const float inv = 1.0f / (float)NTOT;
  float mean = s * inv;
  float var = q * inv - mean * mean;
  float a = g[c] / sqrtf(var + 1e-5f);
  float bb = be[c] - mean * a;
  statsF[((size_t)layer * 128 + c) * 2]     = a;
  statsF[((size_t)layer * 128 + c) * 2 + 1] = bb;
}

// ---------------------------------------------------------------------------
__global__ __launch_bounds__(256) void k_pool(const float* __restrict__ maxb,
                                              const float* __restrict__ minb,
                                              const float* __restrict__ statsF,
                                              float* __restrict__ outp) {
  int t = blockIdx.x * 256 + threadIdx.x;
  int c = t & 127;
  float a  = statsF[(2*128 + c)*2];
  float bb = statsF[(2*128 + c)*2 + 1];
  float X = (a >= 0.f) ? maxb[t] : minb[t];
  outp[t] = fmaxf(0.f, fmaf(a, X, bb));
}

// ---------------------------------------------------------------------------
extern "C" void kernel_launch(void* const* d_in, const int* in_sizes, int n_in,
                              void* d_out, int out_size, void* d_ws, size_t ws_size,
                              hipStream_t stream) {
  (void)in_sizes; (void)n_in; (void)out_size; (void)ws_size;
  const float* xyz = (const float*)d_in[0];
  const float* pts = (const float*)d_in[1];
  const float* w0  = (const float*)d_in[2];
  const float* g0  = (const float*)d_in[4];
  const float* be0 = (const float*)d_in[5];
  const float* w1  = (const float*)d_in[6];
  const float* g1  = (const float*)d_in[8];
  const float* be1 = (const float*)d_in[9];
  const float* w2  = (const float*)d_in[10];
  const float* g2  = (const float*)d_in[12];
  const float* be2 = (const float*)d_in[13];

  float* out = (float*)d_out;
  float* newxyz = out;                    // [B,S,3]
  float* pooled = out + (size_t)NB*NS*3;  // [B,S,128]

  float* ws = (float*)d_ws;
  float* pp     = ws;                                 // 65536
  int*   idx    = (int*)(ws + 65536);                 // 524288 ints
  float* part   = ws + 65536 + 524288;                // 131072 reserved
  float* statsF = part + 131072;                      // 768
  float* maxb   = statsF + 768;                       // 2097152
  float* minb   = maxb + 2097152;                     // 2097152
  unsigned* prog = (unsigned*)(minb + 2097152);       // 8 progress + flag
  unsigned* flag = prog + 8;

  k_stage1<<<256, 256, 0, stream>>>(xyz, pts, w0, newxyz, pp, idx, part, prog, flag);
  k_fin<<<1, 128, 0, stream>>>(part, NCONS, g0, be0, statsF, 0, 64);
  k_l1stats<<<512, 256, 0, stream>>>(xyz, pts, newxyz, idx, w0, w1, statsF, part);
  k_fin<<<1, 128, 0, stream>>>(part, 512, g1, be1, statsF, 1, 64);
  k_l2<<<256, 256, 0, stream>>>(xyz, pts, newxyz, idx, w0, w1, w2, statsF, part, maxb, minb);
  k_fin<<<1, 128, 0, stream>>>(part, 256, g2, be2, statsF, 2, 128);
  k_pool<<<8192, 256, 0, stream>>>(maxb, minb, statsF, pooled);
}

// Round 11
// 2905.439 us; speedup vs baseline: 1.4016x; 1.2041x over previous
//
#include <hip/hip_runtime.h>

#define NPTS 8192
#define NB 8
#define NS 2048
#define NK 32
#define C0 67
#define NTOT (NB*NS*NK)   // 524288 rows
#define NCONS 248
#define MAGIC 0xC0FFEE01u

// ---- DPP wave64 reduce helpers ---------------------------------------------
template <int CTRL, int ROWM>
__device__ __forceinline__ float dpp_fmax_step(float x) {
  int yi = __builtin_amdgcn_update_dpp(__float_as_int(x), __float_as_int(x),
                                       CTRL, ROWM, 0xf, false);
  return fmaxf(x, __int_as_float(yi));
}
template <int CTRL, int ROWM>
__device__ __forceinline__ unsigned dpp_umin_step(unsigned x) {
  unsigned y = (unsigned)__builtin_amdgcn_update_dpp((int)x, (int)x,
                                                     CTRL, ROWM, 0xf, false);
  return (y < x) ? y : x;
}
__device__ __forceinline__ float wave_max_f32(float v) {
  v = dpp_fmax_step<0x111, 0xf>(v);
  v = dpp_fmax_step<0x112, 0xf>(v);
  v = dpp_fmax_step<0x114, 0xf>(v);
  v = dpp_fmax_step<0x118, 0xf>(v);
  v = dpp_fmax_step<0x142, 0xa>(v);
  v = dpp_fmax_step<0x143, 0xc>(v);
  return v;
}
__device__ __forceinline__ unsigned wave_min_u32(unsigned v) {
  v = dpp_umin_step<0x111, 0xf>(v);
  v = dpp_umin_step<0x112, 0xf>(v);
  v = dpp_umin_step<0x114, 0xf>(v);
  v = dpp_umin_step<0x118, 0xf>(v);
  v = dpp_umin_step<0x142, 0xa>(v);
  v = dpp_umin_step<0x143, 0xc>(v);
  return v;
}

// ===========================================================================
// ============================ PATH A (streamed x0) =========================
// ===========================================================================
union SMemA {
  struct {
    float sx[NPTS], sy[NPTS], sz[NPTS];
    float snx[NS], sny[NS], snz[NS];
    uint2 slotVN[2][4];
  } fps;
  struct {
    float w0t[C0*64];
    float feat[C0*32];
    int   bq[4][32];
    int   bqc[4];
    int   s_idx[32];
    float s_c[3];
  } con;
};

// Stage1: FPS producers (blocks 0..7) + consumers (8..255): BQ + gather +
// L0 GEMM -> stream raw x0 to global + stats0; last consumer computes statsF0.
__global__ __launch_bounds__(256, 1) void k_stage1A(
    const float* __restrict__ xyz, const float* __restrict__ pts,
    const float* __restrict__ w0, const float* __restrict__ g0,
    const float* __restrict__ be0,
    float* __restrict__ newxyz, float* __restrict__ pp,
    float* __restrict__ x0, float* __restrict__ part,
    float* __restrict__ statsF, unsigned* __restrict__ sync) {
  __shared__ __align__(16) SMemA sm;
  __shared__ int s_last;
  const int tid = threadIdx.x;
  unsigned* prog = sync;           // [0..7] zeroed by memset
  unsigned* ctr0 = sync + 8;

  if (blockIdx.x < NB) {
    // ===================== PRODUCER: FPS =====================
    const int b = blockIdx.x;
    const int wv = tid >> 6, lane = tid & 63;
    const float* Xb = xyz + (size_t)b * NPTS * 3;
    float px[32], py[32], pz[32], mind[32];
#pragma unroll
    for (int k = 0; k < 32; k++) {
      int n = (k << 8) | tid;
      float x = Xb[n*3+0], y = Xb[n*3+1], z = Xb[n*3+2];
      px[k]=x; py[k]=y; pz[k]=z;
      sm.fps.sx[n]=x; sm.fps.sy[n]=y; sm.fps.sz[n]=z;
      pp[b*NPTS + n] = __fadd_rn(__fadd_rn(__fmul_rn(x,x), __fmul_rn(y,y)), __fmul_rn(z,z));
      mind[k] = 1e10f;
    }
    __syncthreads();
    float lx = sm.fps.sx[0], ly = sm.fps.sy[0], lz = sm.fps.sz[0];
    if (tid == 0) { sm.fps.snx[0]=lx; sm.fps.sny[0]=ly; sm.fps.snz[0]=lz; }
    for (int s = 1; s < NS; s++) {
      float m32[32];
#pragma unroll
      for (int k = 0; k < 32; k++) {
        float dx = __fsub_rn(px[k], lx);
        float dy = __fsub_rn(py[k], ly);
        float dz = __fsub_rn(pz[k], lz);
        float d = __fadd_rn(__fadd_rn(__fmul_rn(dx,dx), __fmul_rn(dy,dy)), __fmul_rn(dz,dz));
        float m = fminf(mind[k], d);
        mind[k] = m;
        m32[k] = m;
      }
#pragma unroll
      for (int st = 16; st >= 1; st >>= 1)
#pragma unroll
        for (int k = 0; k < st; k++) m32[k] = fmaxf(m32[k], m32[k + st]);
      float v = m32[0];
      float vr = wave_max_f32(v);
      float wmax = __int_as_float(__builtin_amdgcn_readlane(__float_as_int(vr), 63));
      int kk = 31;
#pragma unroll
      for (int k = 30; k >= 0; k--) kk = (mind[k] == v) ? k : kk;
      unsigned ncand = (v == wmax) ? (unsigned)((kk << 8) | tid) : 0xffffffffu;
      unsigned nr = wave_min_u32(ncand);
      int buf = s & 1;
      if (lane == 63) sm.fps.slotVN[buf][wv] = make_uint2(__float_as_uint(vr), nr);
      __syncthreads();
      uint4 s01 = *(const uint4*)&sm.fps.slotVN[buf][0];
      uint4 s23 = *(const uint4*)&sm.fps.slotVN[buf][2];
      unsigned bx = s01.x, by = s01.y;
      if (s01.z > bx || (s01.z == bx && s01.w < by)) { bx = s01.z; by = s01.w; }
      if (s23.x > bx || (s23.x == bx && s23.y < by)) { bx = s23.x; by = s23.y; }
      if (s23.z > bx || (s23.z == bx && s23.w < by)) { bx = s23.z; by = s23.w; }
      int n = (int)by;
      lx = sm.fps.sx[n]; ly = sm.fps.sy[n]; lz = sm.fps.sz[n];
      if (tid == 0) { sm.fps.snx[s]=lx; sm.fps.sny[s]=ly; sm.fps.snz[s]=lz; }
      if ((s & 63) == 63) {
        __syncthreads();
        int cs = s - 63;
        if (tid < 192) {
          int e = cs + tid / 3, comp = tid - (tid / 3) * 3;
          float vvv = (comp == 0) ? sm.fps.snx[e] : ((comp == 1) ? sm.fps.sny[e] : sm.fps.snz[e]);
          newxyz[((size_t)b*NS + cs)*3 + tid] = vvv;
        }
        __syncthreads();
        if (tid == 0) {
          __threadfence();
          __hip_atomic_store(&prog[b], (unsigned)(s + 1), __ATOMIC_RELEASE, __HIP_MEMORY_SCOPE_AGENT);
        }
      }
    }
  } else {
    // ===================== CONSUMER: BQ + L0 -> x0 stream =====================
    const int cb = blockIdx.x - NB;          // 0..247
    const int wv = tid >> 6, lane = tid & 63;
    float* w0t = sm.con.w0t;
    float* feat = sm.con.feat;
    for (int t = tid; t < C0*64; t += 256) { int j = t >> 6, c = t & 63; w0t[t] = w0[c*C0 + j]; }
    int rt = tid & 7, ct = tid >> 3;
    float s0[2] = {0,0}, q0[2] = {0,0};
    for (int it = 0; it <= 66; it++) {
      int e = cb + NCONS * it;
      if (e >= NB*NS) break;
      int s = e >> 3, b = e & 7;
      size_t row = (size_t)b * NS + s;
      if (tid == 0) {
        while ((int)__hip_atomic_load(&prog[b], __ATOMIC_ACQUIRE, __HIP_MEMORY_SCOPE_AGENT) <= s)
          __builtin_amdgcn_s_sleep(32);
        __threadfence();
      }
      __syncthreads();
      const float* c3 = newxyz + row * 3;
      float cx = c3[0], cy = c3[1], cz = c3[2];
      float qq = __fadd_rn(__fadd_rn(__fmul_rn(cx,cx), __fmul_rn(cy,cy)), __fmul_rn(cz,cz));
      const float* Xb = xyz + (size_t)b * NPTS * 3;
      const float* Pb = pp + b * NPTS;
      int cnt = 0;
      int base = wv << 11;
      for (int j0 = base; j0 < base + 2048; j0 += 64) {
        int n = j0 + lane;
        float x = Xb[n*3+0], y = Xb[n*3+1], z = Xb[n*3+2];
        float dot = __fadd_rn(__fadd_rn(__fmul_rn(cx,x), __fmul_rn(cy,y)), __fmul_rn(cz,z));
        float d2 = __fsub_rn(__fadd_rn(qq, Pb[n]), __fmul_rn(2.0f, dot));
        bool in = (d2 <= 0.0625f);
        unsigned long long bal = __ballot(in);
        if (in) {
          int pos = cnt + (int)__popcll(bal & ((1ull << lane) - 1ull));
          if (pos < NK) sm.con.bq[wv][pos] = n;
        }
        cnt += (int)__popcll(bal);
        if (cnt >= NK) break;
      }
      if (lane == 0) sm.con.bqc[wv] = (cnt < NK) ? cnt : NK;
      __syncthreads();
      if (tid < NK) {
        int l0 = sm.con.bqc[0], l1 = sm.con.bqc[1], l2 = sm.con.bqc[2], l3 = sm.con.bqc[3];
        int t1 = l0 + l1, t2 = t1 + l2, t3 = t2 + l3;
        int j = tid, v;
        if (j < l0)      v = sm.con.bq[0][j];
        else if (j < t1) v = sm.con.bq[1][j - l0];
        else if (j < t2) v = sm.con.bq[2][j - t1];
        else if (j < t3) v = sm.con.bq[3][j - t2];
        else {
          v = (l0 > 0) ? sm.con.bq[0][0] : (l1 > 0) ? sm.con.bq[1][0]
            : (l2 > 0) ? sm.con.bq[2][0] : (l3 > 0) ? sm.con.bq[3][0] : 0;
        }
        sm.con.s_idx[j] = v;
      }
      if (tid >= 32 && tid < 35) sm.con.s_c[tid - 32] = c3[tid - 32];
      __syncthreads();
      if (tid < 32) {
        const float* p = &xyz[((size_t)b*NPTS + sm.con.s_idx[tid])*3];
        feat[0*32+tid] = p[0] - sm.con.s_c[0];
        feat[1*32+tid] = p[1] - sm.con.s_c[1];
        feat[2*32+tid] = p[2] - sm.con.s_c[2];
      }
      {
        int r_ = tid & 31, cq_ = tid >> 5;
        const float* pr = &pts[((size_t)b*NPTS + sm.con.s_idx[r_])*64 + cq_*8];
        float4 A_ = *(const float4*)pr;
        float4 B_ = *(const float4*)(pr + 4);
        feat[(3+cq_*8+0)*32 + r_] = A_.x;
        feat[(3+cq_*8+1)*32 + r_] = A_.y;
        feat[(3+cq_*8+2)*32 + r_] = A_.z;
        feat[(3+cq_*8+3)*32 + r_] = A_.w;
        feat[(3+cq_*8+4)*32 + r_] = B_.x;
        feat[(3+cq_*8+5)*32 + r_] = B_.y;
        feat[(3+cq_*8+6)*32 + r_] = B_.z;
        feat[(3+cq_*8+7)*32 + r_] = B_.w;
      }
      __syncthreads();
      float acc[4][2] = {};
      for (int j = 0; j < C0; j++) {
        float4 av = *(const float4*)&feat[j*32 + rt*4];
        float2 wvv = *(const float2*)&w0t[j*64 + ct*2];
        float aa[4] = {av.x, av.y, av.z, av.w};
#pragma unroll
        for (int r = 0; r < 4; r++) {
          acc[r][0] = fmaf(aa[r], wvv.x, acc[r][0]);
          acc[r][1] = fmaf(aa[r], wvv.y, acc[r][1]);
        }
      }
      // stream raw x0 (pre-BN) + accumulate stats
      float* dst = x0 + row * 2048;
#pragma unroll
      for (int r = 0; r < 4; r++)
#pragma unroll
        for (int u = 0; u < 2; u++) {
          float x = acc[r][u];
          dst[(rt*4+r)*64 + ct*2+u] = x;
          s0[u] += x; q0[u] = fmaf(x, x, q0[u]);
        }
      __syncthreads();
    }
#pragma unroll
    for (int off = 1; off < 8; off <<= 1) {
#pragma unroll
      for (int u = 0; u < 2; u++) { s0[u] += __shfl_xor(s0[u], off, 64); q0[u] += __shfl_xor(q0[u], off, 64); }
    }
    if (rt == 0) {
#pragma unroll
      for (int u = 0; u < 2; u++) {
        size_t o = ((size_t)cb * 128 + ct*2 + u) * 2;
        part[o] = s0[u]; part[o+1] = q0[u];
      }
    }
    // ---- fused fin0: last consumer block reduces partials -> statsF0 ----
    __threadfence();
    if (tid == 0) {
      unsigned old = __hip_atomic_fetch_add(ctr0, 1u, __ATOMIC_ACQ_REL, __HIP_MEMORY_SCOPE_AGENT);
      s_last = (old == NCONS - 1);
    }
    __syncthreads();
    if (s_last) {
      __threadfence();
      if (tid < 64) {
        float s = 0.f, q = 0.f;
        for (int k = 0; k < NCONS; k++) {
          s += part[((size_t)k * 128 + tid) * 2];
          q += part[((size_t)k * 128 + tid) * 2 + 1];
        }
        const float inv = 1.0f / (float)NTOT;
        float mean = s * inv;
        float var = q * inv - mean * mean;
        float a = g0[tid] / sqrtf(var + 1e-5f);
        float bb = be0[tid] - mean * a;
        statsF[tid*2] = a; statsF[tid*2 + 1] = bb;
      }
    }
  }
}

// L1 pass (path A): read x0, BN0+ReLU, L1 GEMM, stats1; fused fin1.
__global__ __launch_bounds__(256) void k_l1x(
    const float* __restrict__ x0, const float* __restrict__ w1,
    const float* __restrict__ g1, const float* __restrict__ be1,
    float* __restrict__ statsF, float* __restrict__ part,
    unsigned* __restrict__ sync) {
  __shared__ __align__(16) float w1t[64*64];
  __shared__ __align__(16) float x0n[64*32];
  __shared__ float sF[128];
  __shared__ int s_last;
  unsigned* ctr1 = sync + 9;
  int tid = threadIdx.x;
  for (int t = tid; t < 64*64; t += 256) { int j = t >> 6, c = t & 63; w1t[t] = w1[c*64 + j]; }
  if (tid < 64) { sF[tid] = statsF[tid*2]; sF[64+tid] = statsF[tid*2+1]; }
  int rt = tid & 7, ct = tid >> 3;
  float s1[2] = {0,0}, q1[2] = {0,0};
  for (int g = 0; g < 32; g++) {
    size_t gid = (size_t)blockIdx.x * 32 + g;
    __syncthreads();   // protect x0n reuse
    const float* src = x0 + gid * 2048;
#pragma unroll
    for (int i = 0; i < 2; i++) {
      int local = tid*8 + i*4;
      float4 v = *(const float4*)(src + local);
      int row = local >> 6, col = local & 63;
      x0n[(col+0)*32+row] = fmaxf(0.f, fmaf(v.x, sF[col+0], sF[64+col+0]));
      x0n[(col+1)*32+row] = fmaxf(0.f, fmaf(v.y, sF[col+1], sF[64+col+1]));
      x0n[(col+2)*32+row] = fmaxf(0.f, fmaf(v.z, sF[col+2], sF[64+col+2]));
      x0n[(col+3)*32+row] = fmaxf(0.f, fmaf(v.w, sF[col+3], sF[64+col+3]));
    }
    __syncthreads();
    float acc[4][2] = {};
    for (int j = 0; j < 64; j++) {
      float4 av = *(const float4*)&x0n[j*32 + rt*4];
      float2 wv = *(const float2*)&w1t[j*64 + ct*2];
      float aa[4] = {av.x, av.y, av.z, av.w};
#pragma unroll
      for (int r = 0; r < 4; r++) {
        acc[r][0] = fmaf(aa[r], wv.x, acc[r][0]);
        acc[r][1] = fmaf(aa[r], wv.y, acc[r][1]);
      }
    }
#pragma unroll
    for (int r = 0; r < 4; r++)
#pragma unroll
      for (int u = 0; u < 2; u++) { float x = acc[r][u]; s1[u] += x; q1[u] = fmaf(x, x, q1[u]); }
  }
#pragma unroll
  for (int off = 1; off < 8; off <<= 1) {
#pragma unroll
    for (int u = 0; u < 2; u++) { s1[u] += __shfl_xor(s1[u], off, 64); q1[u] += __shfl_xor(q1[u], off, 64); }
  }
  if (rt == 0) {
#pragma unroll
    for (int u = 0; u < 2; u++) {
      size_t o = ((size_t)blockIdx.x * 128 + ct*2 + u) * 2;
      part[o] = s1[u]; part[o+1] = q1[u];
    }
  }
  __threadfence();
  if (tid == 0) {
    unsigned old = __hip_atomic_fetch_add(ctr1, 1u, __ATOMIC_ACQ_REL, __HIP_MEMORY_SCOPE_AGENT);
    s_last = (old == 511);
  }
  __syncthreads();
  if (s_last) {
    __threadfence();
    if (tid < 64) {
      float s = 0.f, q = 0.f;
      for (int k = 0; k < 512; k++) {
        s += part[((size_t)k * 128 + tid) * 2];
        q += part[((size_t)k * 128 + tid) * 2 + 1];
      }
      const float inv = 1.0f / (float)NTOT;
      float mean = s * inv;
      float var = q * inv - mean * mean;
      float a = g1[tid] / sqrtf(var + 1e-5f);
      float bb = be1[tid] - mean * a;
      statsF[(128 + tid)*2] = a; statsF[(128 + tid)*2 + 1] = bb;
    }
  }
}

// L2 pass (path A): read x0, BN0 -> L1 -> BN1 -> L2; stats2 + max/min; fin2.
__global__ __launch_bounds__(256) void k_l2x(
    const float* __restrict__ x0, const float* __restrict__ w1,
    const float* __restrict__ w2, const float* __restrict__ g2,
    const float* __restrict__ be2,
    float* __restrict__ statsF, float* __restrict__ part,
    float* __restrict__ maxb, float* __restrict__ minb,
    unsigned* __restrict__ sync) {
  __shared__ __align__(16) float w1t[64*64];
  __shared__ __align__(16) float w2t[64*128];
  __shared__ __align__(16) float x0n[64*32];
  __shared__ __align__(16) float x1n[64*32];
  __shared__ float sF[256];   // a0,b0,a1,b1 each 64
  __shared__ int s_last;
  unsigned* ctr2 = sync + 10;
  int tid = threadIdx.x;
  for (int t = tid; t < 64*64; t += 256) { int j = t >> 6, c = t & 63; w1t[t] = w1[c*64 + j]; }
  for (int t = tid; t < 64*128; t += 256) { int j = t >> 7, c = t & 127; w2t[t] = w2[c*64 + j]; }
  if (tid < 64) {
    sF[tid]       = statsF[tid*2];            sF[64+tid]  = statsF[tid*2+1];
    sF[128+tid]   = statsF[(128+tid)*2];      sF[192+tid] = statsF[(128+tid)*2+1];
  }
  int rt = tid & 7, ct = tid >> 3;
  float a1c[2], b1c[2];
  float s2[4] = {0,0,0,0}, q2[4] = {0,0,0,0};
  __syncthreads();
#pragma unroll
  for (int u = 0; u < 2; u++) { a1c[u] = sF[128 + ct*2+u]; b1c[u] = sF[192 + ct*2+u]; }
  for (int g = 0; g < 64; g++) {
    size_t gid = (size_t)blockIdx.x * 64 + g;
    __syncthreads();   // protect x0n/x1n reuse
    const float* src = x0 + gid * 2048;
#pragma unroll
    for (int i = 0; i < 2; i++) {
      int local = tid*8 + i*4;
      float4 v = *(const float4*)(src + local);
      int row = local >> 6, col = local & 63;
      x0n[(col+0)*32+row] = fmaxf(0.f, fmaf(v.x, sF[col+0], sF[64+col+0]));
      x0n[(col+1)*32+row] = fmaxf(0.f, fmaf(v.y, sF[col+1], sF[64+col+1]));
      x0n[(col+2)*32+row] = fmaxf(0.f, fmaf(v.z, sF[col+2], sF[64+col+2]));
      x0n[(col+3)*32+row] = fmaxf(0.f, fmaf(v.w, sF[col+3], sF[64+col+3]));
    }
    __syncthreads();
    {
      float acc[4][2] = {};
      for (int j = 0; j < 64; j++) {
        float4 av = *(const float4*)&x0n[j*32 + rt*4];
        float2 wv = *(const float2*)&w1t[j*64 + ct*2];
        float aa[4] = {av.x, av.y, av.z, av.w};
#pragma unroll
        for (int r = 0; r < 4; r++) {
          acc[r][0] = fmaf(aa[r], wv.x, acc[r][0]);
          acc[r][1] = fmaf(aa[r], wv.y, acc[r][1]);
        }
      }
#pragma unroll
      for (int u = 0; u < 2; u++) {
        float4 st;
        st.x = fmaxf(0.f, fmaf(acc[0][u], a1c[u], b1c[u]));
        st.y = fmaxf(0.f, fmaf(acc[1][u], a1c[u], b1c[u]));
        st.z = fmaxf(0.f, fmaf(acc[2][u], a1c[u], b1c[u]));
        st.w = fmaxf(0.f, fmaf(acc[3][u], a1c[u], b1c[u]));
        *(float4*)&x1n[(ct*2 + u)*32 + rt*4] = st;
      }
    }
    __syncthreads();
    {
      float acc[4][4] = {};
      for (int j = 0; j < 64; j++) {
        float4 av = *(const float4*)&x1n[j*32 + rt*4];
        float4 wvv = *(const float4*)&w2t[j*128 + ct*4];
        float aa[4] = {av.x, av.y, av.z, av.w};
        float ww[4] = {wvv.x, wvv.y, wvv.z, wvv.w};
#pragma unroll
        for (int r = 0; r < 4; r++)
#pragma unroll
          for (int u = 0; u < 4; u++) acc[r][u] = fmaf(aa[r], ww[u], acc[r][u]);
      }
      float mx[4], mn[4];
#pragma unroll
      for (int u = 0; u < 4; u++) {
        float x0v = acc[0][u], x1v = acc[1][u], x2v = acc[2][u], x3v = acc[3][u];
        s2[u] += ((x0v + x1v) + (x2v + x3v));
        q2[u] = fmaf(x0v, x0v, q2[u]); q2[u] = fmaf(x1v, x1v, q2[u]);
        q2[u] = fmaf(x2v, x2v, q2[u]); q2[u] = fmaf(x3v, x3v, q2[u]);
        mx[u] = fmaxf(fmaxf(x0v, x1v), fmaxf(x2v, x3v));
        mn[u] = fminf(fminf(x0v, x1v), fminf(x2v, x3v));
      }
#pragma unroll
      for (int off = 1; off < 8; off <<= 1) {
#pragma unroll
        for (int u = 0; u < 4; u++) {
          mx[u] = fmaxf(mx[u], __shfl_xor(mx[u], off, 64));
          mn[u] = fminf(mn[u], __shfl_xor(mn[u], off, 64));
        }
      }
      if (rt == 0) {
#pragma unroll
        for (int u = 0; u < 4; u++) {
          maxb[gid*128 + ct*4 + u] = mx[u];
          minb[gid*128 + ct*4 + u] = mn[u];
        }
      }
    }
  }
#pragma unroll
  for (int off = 1; off < 8; off <<= 1) {
#pragma unroll
    for (int u = 0; u < 4; u++) { s2[u] += __shfl_xor(s2[u], off, 64); q2[u] += __shfl_xor(q2[u], off, 64); }
  }
  if (rt == 0) {
#pragma unroll
    for (int u = 0; u < 4; u++) {
      size_t o = ((size_t)blockIdx.x * 128 + ct*4 + u) * 2;
      part[o] = s2[u]; part[o+1] = q2[u];
    }
  }
  __threadfence();
  if (tid == 0) {
    unsigned old = __hip_atomic_fetch_add(ctr2, 1u, __ATOMIC_ACQ_REL, __HIP_MEMORY_SCOPE_AGENT);
    s_last = (old == 255);
  }
  __syncthreads();
  if (s_last) {
    __threadfence();
    if (tid < 128) {
      float s = 0.f, q = 0.f;
      for (int k = 0; k < 256; k++) {
        s += part[((size_t)k * 128 + tid) * 2];
        q += part[((size_t)k * 128 + tid) * 2 + 1];
      }
      const float inv = 1.0f / (float)NTOT;
      float mean = s * inv;
      float var = q * inv - mean * mean;
      float a = g2[tid] / sqrtf(var + 1e-5f);
      float bb = be2[tid] - mean * a;
      statsF[(256 + tid)*2] = a; statsF[(256 + tid)*2 + 1] = bb;
    }
  }
}

// Pool epilogue (both paths): pooled = relu(a*X + beta), X = a>=0 ? max : min.
__global__ __launch_bounds__(256) void k_pool(const float* __restrict__ maxb,
                                              const float* __restrict__ minb,
                                              const float* __restrict__ statsF,
                                              float* __restrict__ outp) {
  int t = blockIdx.x * 256 + threadIdx.x;
  int c = t & 127;
  float a  = statsF[(2*128 + c)*2];
  float bb = statsF[(2*128 + c)*2 + 1];
  float X = (a >= 0.f) ? maxb[t] : minb[t];
  outp[t] = fmaxf(0.f, fmaf(a, X, bb));
}

// ===========================================================================
// ======================= PATH B (R10, proven fallback) =====================
// ===========================================================================
union SMem1 {
  struct {
    float sx[NPTS], sy[NPTS], sz[NPTS];
    float snx[NS], sny[NS], snz[NS];
    uint2 slotVN[2][4];
  } fps;
  struct {
    float w0t[C0*64];
    float feat[C0*32];
    int   bq[4][32];
    int   bqc[4];
    int   s_idx[32];
    float s_c[3];
  } con;
};

__global__ __launch_bounds__(256, 1) void k_stage1(
    const float* __restrict__ xyz, const float* __restrict__ pts,
    const float* __restrict__ w0,
    float* __restrict__ newxyz, float* __restrict__ pp, int* __restrict__ idx,
    float* __restrict__ part, unsigned* __restrict__ prog,
    unsigned* __restrict__ flag) {
  __shared__ __align__(16) SMem1 sm;
  const int tid = threadIdx.x;
  if (blockIdx.x == 0 && tid == 0) {
    for (int i = 0; i < NB; i++)
      __hip_atomic_store(&prog[i], 0u, __ATOMIC_RELAXED, __HIP_MEMORY_SCOPE_AGENT);
    __threadfence();
    __hip_atomic_store(flag, MAGIC, __ATOMIC_RELEASE, __HIP_MEMORY_SCOPE_AGENT);
  }
  if (tid == 0) {
    while (__hip_atomic_load(flag, __ATOMIC_ACQUIRE, __HIP_MEMORY_SCOPE_AGENT) != MAGIC)
      __builtin_amdgcn_s_sleep(8);
  }
  __syncthreads();

  if (blockIdx.x < NB) {
    const int b = blockIdx.x;
    const int wv = tid >> 6, lane = tid & 63;
    const float* Xb = xyz + (size_t)b * NPTS * 3;
    float px[32], py[32], pz[32], mind[32];
#pragma unroll
    for (int k = 0; k < 32; k++) {
      int n = (k << 8) | tid;
      float x = Xb[n*3+0], y = Xb[n*3+1], z = Xb[n*3+2];
      px[k]=x; py[k]=y; pz[k]=z;
      sm.fps.sx[n]=x; sm.fps.sy[n]=y; sm.fps.sz[n]=z;
      pp[b*NPTS + n] = __fadd_rn(__fadd_rn(__fmul_rn(x,x), __fmul_rn(y,y)), __fmul_rn(z,z));
      mind[k] = 1e10f;
    }
    __syncthreads();
    float lx = sm.fps.sx[0], ly = sm.fps.sy[0], lz = sm.fps.sz[0];
    if (tid == 0) { sm.fps.snx[0]=lx; sm.fps.sny[0]=ly; sm.fps.snz[0]=lz; }
    for (int s = 1; s < NS; s++) {
      float m32[32];
#pragma unroll
      for (int k = 0; k < 32; k++) {
        float dx = __fsub_rn(px[k], lx);
        float dy = __fsub_rn(py[k], ly);
        float dz = __fsub_rn(pz[k], lz);
        float d = __fadd_rn(__fadd_rn(__fmul_rn(dx,dx), __fmul_rn(dy,dy)), __fmul_rn(dz,dz));
        float m = fminf(mind[k], d);
        mind[k] = m;
        m32[k] = m;
      }
#pragma unroll
      for (int st = 16; st >= 1; st >>= 1)
#pragma unroll
        for (int k = 0; k < st; k++) m32[k] = fmaxf(m32[k], m32[k + st]);
      float v = m32[0];
      float vr = wave_max_f32(v);
      float wmax = __int_as_float(__builtin_amdgcn_readlane(__float_as_int(vr), 63));
      int kk = 31;
#pragma unroll
      for (int k = 30; k >= 0; k--) kk = (mind[k] == v) ? k : kk;
      unsigned ncand = (v == wmax) ? (unsigned)((kk << 8) | tid) : 0xffffffffu;
      unsigned nr = wave_min_u32(ncand);
      int buf = s & 1;
      if (lane == 63) sm.fps.slotVN[buf][wv] = make_uint2(__float_as_uint(vr), nr);
      __syncthreads();
      uint4 s01 = *(const uint4*)&sm.fps.slotVN[buf][0];
      uint4 s23 = *(const uint4*)&sm.fps.slotVN[buf][2];
      unsigned bx = s01.x, by = s01.y;
      if (s01.z > bx || (s01.z == bx && s01.w < by)) { bx = s01.z; by = s01.w; }
      if (s23.x > bx || (s23.x == bx && s23.y < by)) { bx = s23.x; by = s23.y; }
      if (s23.z > bx || (s23.z == bx && s23.w < by)) { bx = s23.z; by = s23.w; }
      int n = (int)by;
      lx = sm.fps.sx[n]; ly = sm.fps.sy[n]; lz = sm.fps.sz[n];
      if (tid == 0) { sm.fps.snx[s]=lx; sm.fps.sny[s]=ly; sm.fps.snz[s]=lz; }
      if ((s & 63) == 63) {
        __syncthreads();
        int cs = s - 63;
        if (tid < 192) {
          int e = cs + tid / 3, comp = tid - (tid / 3) * 3;
          float vvv = (comp == 0) ? sm.fps.snx[e] : ((comp == 1) ? sm.fps.sny[e] : sm.fps.snz[e]);
          newxyz[((size_t)b*NS + cs)*3 + tid] = vvv;
        }
        __syncthreads();
        if (tid == 0) {
          __threadfence();
          __hip_atomic_store(&prog[b], (unsigned)(s + 1), __ATOMIC_RELEASE, __HIP_MEMORY_SCOPE_AGENT);
        }
      }
    }
  } else {
    const int cb = blockIdx.x - NB;
    const int wv = tid >> 6, lane = tid & 63;
    float* w0t = sm.con.w0t;
    float* feat = sm.con.feat;
    for (int t = tid; t < C0*64; t += 256) { int j = t >> 6, c = t & 63; w0t[t] = w0[c*C0 + j]; }
    int rt = tid & 7, ct = tid >> 3;
    float s0[2] = {0,0}, q0[2] = {0,0};
    for (int it = 0; it <= 66; it++) {
      int e = cb + NCONS * it;
      if (e >= NB*NS) break;
      int s = e >> 3, b = e & 7;
      size_t row = (size_t)b * NS + s;
      if (tid == 0) {
        while ((int)__hip_atomic_load(&prog[b], __ATOMIC_ACQUIRE, __HIP_MEMORY_SCOPE_AGENT) <= s)
          __builtin_amdgcn_s_sleep(32);
        __threadfence();
      }
      __syncthreads();
      const float* c3 = newxyz + row * 3;
      float cx = c3[0], cy = c3[1], cz = c3[2];
      float qq = __fadd_rn(__fadd_rn(__fmul_rn(cx,cx), __fmul_rn(cy,cy)), __fmul_rn(cz,cz));
      const float* Xb = xyz + (size_t)b * NPTS * 3;
      const float* Pb = pp + b * NPTS;
      int cnt = 0;
      int base = wv << 11;
      for (int j0 = base; j0 < base + 2048; j0 += 64) {
        int n = j0 + lane;
        float x = Xb[n*3+0], y = Xb[n*3+1], z = Xb[n*3+2];
        float dot = __fadd_rn(__fadd_rn(__fmul_rn(cx,x), __fmul_rn(cy,y)), __fmul_rn(cz,z));
        float d2 = __fsub_rn(__fadd_rn(qq, Pb[n]), __fmul_rn(2.0f, dot));
        bool in = (d2 <= 0.0625f);
        unsigned long long bal = __ballot(in);
        if (in) {
          int pos = cnt + (int)__popcll(bal & ((1ull << lane) - 1ull));
          if (pos < NK) sm.con.bq[wv][pos] = n;
        }
        cnt += (int)__popcll(bal);
        if (cnt >= NK) break;
      }
      if (lane == 0) sm.con.bqc[wv] = (cnt < NK) ? cnt : NK;
      __syncthreads();
      if (tid < NK) {
        int l0 = sm.con.bqc[0], l1 = sm.con.bqc[1], l2 = sm.con.bqc[2], l3 = sm.con.bqc[3];
        int t1 = l0 + l1, t2 = t1 + l2, t3 = t2 + l3;
        int j = tid, v;
        if (j < l0)      v = sm.con.bq[0][j];
        else if (j < t1) v = sm.con.bq[1][j - l0];
        else if (j < t2) v = sm.con.bq[2][j - t1];
        else if (j < t3) v = sm.con.bq[3][j - t2];
        else {
          v = (l0 > 0) ? sm.con.bq[0][0] : (l1 > 0) ? sm.con.bq[1][0]
            : (l2 > 0) ? sm.con.bq[2][0] : (l3 > 0) ? sm.con.bq[3][0] : 0;
        }
        sm.con.s_idx[j] = v;
        idx[row * NK + j] = v;
      }
      if (tid >= 32 && tid < 35) sm.con.s_c[tid - 32] = c3[tid - 32];
      __syncthreads();
      if (tid < 32) {
        const float* p = &xyz[((size_t)b*NPTS + sm.con.s_idx[tid])*3];
        feat[0*32+tid] = p[0] - sm.con.s_c[0];
        feat[1*32+tid] = p[1] - sm.con.s_c[1];
        feat[2*32+tid] = p[2] - sm.con.s_c[2];
      }
      {
        int r_ = tid & 31, cq_ = tid >> 5;
        const float* pr = &pts[((size_t)b*NPTS + sm.con.s_idx[r_])*64 + cq_*8];
        float4 A_ = *(const float4*)pr;
        float4 B_ = *(const float4*)(pr + 4);
        feat[(3+cq_*8+0)*32 + r_] = A_.x;
        feat[(3+cq_*8+1)*32 + r_] = A_.y;
        feat[(3+cq_*8+2)*32 + r_] = A_.z;
        feat[(3+cq_*8+3)*32 + r_] = A_.w;
        feat[(3+cq_*8+4)*32 + r_] = B_.x;
        feat[(3+cq_*8+5)*32 + r_] = B_.y;
        feat[(3+cq_*8+6)*32 + r_] = B_.z;
        feat[(3+cq_*8+7)*32 + r_] = B_.w;
      }
      __syncthreads();
      float acc[4][2] = {};
      for (int j = 0; j < C0; j++) {
        float4 av = *(const float4*)&feat[j*32 + rt*4];
        float2 wvv = *(const float2*)&w0t[j*64 + ct*2];
        float aa[4] = {av.x, av.y, av.z, av.w};
#pragma unroll
        for (int r = 0; r < 4; r++) {
          acc[r][0] = fmaf(aa[r], wvv.x, acc[r][0]);
          acc[r][1] = fmaf(aa[r], wvv.y, acc[r][1]);
        }
      }
#pragma unroll
      for (int r = 0; r < 4; r++)
#pragma unroll
        for (int u = 0; u < 2; u++) { float x = acc[r][u]; s0[u] += x; q0[u] = fmaf(x, x, q0[u]); }
      __syncthreads();
    }
#pragma unroll
    for (int off = 1; off < 8; off <<= 1) {
#pragma unroll
      for (int u = 0; u < 2; u++) { s0[u] += __shfl_xor(s0[u], off, 64); q0[u] += __shfl_xor(q0[u], off, 64); }
    }
    if (rt == 0) {
#pragma unroll
      for (int u = 0; u < 2; u++) {
        size_t o = ((size_t)cb * 128 + ct*2 + u) * 2;
        part[o] = s0[u]; part[o+1] = q0[u];
      }
    }
  }
}

#define GATHER_GROUP(gid_, b_)                                                   \
  do {                                                                           \
    if (tid < 32) s_idx[tid] = idx[(size_t)(gid_)*NK + tid];                     \
    if (tid < 3)  s_c[tid]   = newxyz[(size_t)(gid_)*3 + tid];                   \
    __syncthreads();                                                             \
    if (tid < 32) {                                                              \
      const float* p = &xyz[((size_t)(b_)*NPTS + s_idx[tid])*3];                 \
      feat[0*32+tid] = p[0] - s_c[0];                                            \
      feat[1*32+tid] = p[1] - s_c[1];                                            \
      feat[2*32+tid] = p[2] - s_c[2];                                            \
    }                                                                            \
    {                                                                            \
      int r_ = tid & 31, cq_ = tid >> 5;                                         \
      const float* pr = &pts[((size_t)(b_)*NPTS + s_idx[r_])*64 + cq_*8];        \
      float4 A_ = *(const float4*)pr;                                            \
      float4 B_ = *(const float4*)(pr + 4);                                      \
      feat[(3+cq_*8+0)*32 + r_] = A_.x;                                          \
      feat[(3+cq_*8+1)*32 + r_] = A_.y;                                          \
      feat[(3+cq_*8+2)*32 + r_] = A_.z;                                          \
      feat[(3+cq_*8+3)*32 + r_] = A_.w;                                          \
      feat[(3+cq_*8+4)*32 + r_] = B_.x;                                          \
      feat[(3+cq_*8+5)*32 + r_] = B_.y;                                          \
      feat[(3+cq_*8+6)*32 + r_] = B_.z;                                          \
      feat[(3+cq_*8+7)*32 + r_] = B_.w;                                          \
    }                                                                            \
    __syncthreads();                                                             \
  } while (0)

__global__ __launch_bounds__(256) void k_l1stats(const float* __restrict__ xyz,
                                                 const float* __restrict__ pts,
                                                 const float* __restrict__ newxyz,
                                                 const int* __restrict__ idx,
                                                 const float* __restrict__ w0,
                                                 const float* __restrict__ w1,
                                                 const float* __restrict__ statsF,
                                                 float* __restrict__ partials) {
  __shared__ __align__(16) float w0t[C0*64];
  __shared__ __align__(16) float w1t[64*64];
  __shared__ __align__(16) float feat[C0*32];
  __shared__ __align__(16) float x0n[64*32];
  __shared__ int s_idx[32];
  __shared__ float s_c[3];
  int tid = threadIdx.x;
  for (int t = tid; t < C0*64; t += 256) { int j = t >> 6, c = t & 63; w0t[t] = w0[c*C0 + j]; }
  for (int t = tid; t < 64*64; t += 256) { int j = t >> 6, c = t & 63; w1t[t] = w1[c*64 + j]; }
  int rt = tid & 7, ct = tid >> 3;
  float a0[2], b0v[2];
#pragma unroll
  for (int u = 0; u < 2; u++) {
    a0[u]  = statsF[(0*128 + ct*2 + u)*2];
    b0v[u] = statsF[(0*128 + ct*2 + u)*2 + 1];
  }
  float s1[2] = {0,0}, q1[2] = {0,0};
  for (int g = 0; g < 32; g++) {
    int gid = blockIdx.x * 32 + g;
    int b = gid >> 11;
    __syncthreads();
    GATHER_GROUP(gid, b);
    {
      float acc[4][2] = {};
      for (int j = 0; j < C0; j++) {
        float4 av = *(const float4*)&feat[j*32 + rt*4];
        float2 wv = *(const float2*)&w0t[j*64 + ct*2];
        float aa[4] = {av.x, av.y, av.z, av.w};
#pragma unroll
        for (int r = 0; r < 4; r++) {
          acc[r][0] = fmaf(aa[r], wv.x, acc[r][0]);
          acc[r][1] = fmaf(aa[r], wv.y, acc[r][1]);
        }
      }
#pragma unroll
      for (int u = 0; u < 2; u++) {
        float4 st;
        st.x = fmaxf(0.f, fmaf(acc[0][u], a0[u], b0v[u]));
        st.y = fmaxf(0.f, fmaf(acc[1][u], a0[u], b0v[u]));
        st.z = fmaxf(0.f, fmaf(acc[2][u], a0[u], b0v[u]));
        st.w = fmaxf(0.f, fmaf(acc[3][u], a0[u], b0v[u]));
        *(float4*)&x0n[(ct*2 + u)*32 + rt*4] = st;
      }
    }
    __syncthreads();
    {
      float acc[4][2] = {};
      for (int j = 0; j < 64; j++) {
        float4 av = *(const float4*)&x0n[j*32 + rt*4];
        float2 wv = *(const float2*)&w1t[j*64 + ct*2];
        float aa[4] = {av.x, av.y, av.z, av.w};
#pragma unroll
        for (int r = 0; r < 4; r++) {
          acc[r][0] = fmaf(aa[r], wv.x, acc[r][0]);
          acc[r][1] = fmaf(aa[r], wv.y, acc[r][1]);
        }
      }
#pragma unroll
      for (int r = 0; r < 4; r++)
#pragma unroll
        for (int u = 0; u < 2; u++) { float x = acc[r][u]; s1[u] += x; q1[u] = fmaf(x, x, q1[u]); }
    }
  }
#pragma unroll
  for (int off = 1; off < 8; off <<= 1) {
#pragma unroll
    for (int u = 0; u < 2; u++) { s1[u] += __shfl_xor(s1[u], off, 64); q1[u] += __shfl_xor(q1[u], off, 64); }
  }
  if (rt == 0) {
#pragma unroll
    for (int u = 0; u < 2; u++) {
      size_t o = ((size_t)blockIdx.x * 128 + ct*2 + u) * 2;
      partials[o] = s1[u]; partials[o+1] = q1[u];
    }
  }
}

__global__ __launch_bounds__(256) void k_l2(const float* __restrict__ xyz,
                                            const float* __restrict__ pts,
                                            const float* __restrict__ newxyz,
                                            const int* __restrict__ idx,
                                            const float* __restrict__ w0,
                                            const float* __restrict__ w1,
                                            const float* __restrict__ w2,
                                            const float* __restrict__ statsF,
                                            float* __restrict__ partials,
                                            float* __restrict__ maxb,
                                            float* __restrict__ minb) {
  __shared__ __align__(16) float w0t[C0*64];
  __shared__ __align__(16) float w1t[64*64];
  __shared__ __align__(16) float w2t[64*128];
  __shared__ __align__(16) float feat[C0*32];
  __shared__ __align__(16) float x0n[64*32];
  __shared__ __align__(16) float x1n[64*32];
  __shared__ int s_idx[32];
  __shared__ float s_c[3];
  int tid = threadIdx.x;
  for (int t = tid; t < C0*64; t += 256) { int j = t >> 6, c = t & 63; w0t[t] = w0[c*C0 + j]; }
  for (int t = tid; t < 64*64; t += 256) { int j = t >> 6, c = t & 63; w1t[t] = w1[c*64 + j]; }
  for (int t = tid; t < 64*128; t += 256) { int j = t >> 7, c = t & 127; w2t[t] = w2[c*64 + j]; }
  int rt = tid & 7, ct = tid >> 3;
  float a0[2], b0v[2], a1[2], b1v[2];
#pragma unroll
  for (int u = 0; u < 2; u++) {
    a0[u]  = statsF[(0*128 + ct*2 + u)*2];
    b0v[u] = statsF[(0*128 + ct*2 + u)*2 + 1];
    a1[u]  = statsF[(1*128 + ct*2 + u)*2];
    b1v[u] = statsF[(1*128 + ct*2 + u)*2 + 1];
  }
  float s2[4] = {0,0,0,0}, q2[4] = {0,0,0,0};
  for (int g = 0; g < 64; g++) {
    int gid = blockIdx.x * 64 + g;
    int b = gid >> 11;
    __syncthreads();
    GATHER_GROUP(gid, b);
    {
      float acc[4][2] = {};
      for (int j = 0; j < C0; j++) {
        float4 av = *(const float4*)&feat[j*32 + rt*4];
        float2 wv = *(const float2*)&w0t[j*64 + ct*2];
        float aa[4] = {av.x, av.y, av.z, av.w};
#pragma unroll
        for (int r = 0; r < 4; r++) {
          acc[r][0] = fmaf(aa[r], wv.x, acc[r][0]);
          acc[r][1] = fmaf(aa[r], wv.y, acc[r][1]);
        }
      }
#pragma unroll
      for (int u = 0; u < 2; u++) {
        float4 st;
        st.x = fmaxf(0.f, fmaf(acc[0][u], a0[u], b0v[u]));
        st.y = fmaxf(0.f, fmaf(acc[1][u], a0[u], b0v[u]));
        st.z = fmaxf(0.f, fmaf(acc[2][u], a0[u], b0v[u]));
        st.w = fmaxf(0.f, fmaf(acc[3][u], a0[u], b0v[u]));
        *(float4*)&x0n[(ct*2 + u)*32 + rt*4] = st;
      }
    }
    __syncthreads();
    {
      float acc[4][2] = {};
      for (int j = 0; j < 64; j++) {
        float4 av = *(const float4*)&x0n[j*32 + rt*4];
        float2 wv = *(const float2*)&w1t[j*64 + ct*2];
        float aa[4] = {av.x, av.y, av.z, av.w};
#pragma unroll
        for (int r = 0; r < 4; r++) {
          acc[r][0] = fmaf(aa[r], wv.x, acc[r][0]);
          acc[r][1] = fmaf(aa[r], wv.y, acc[r][1]);
        }
      }
#pragma unroll
      for (int u = 0; u < 2; u++) {
        float4 st;
        st.x = fmaxf(0.f, fmaf(acc[0][u], a1[u], b1v[u]));
        st.y = fmaxf(0.f, fmaf(acc[1][u], a1[u], b1v[u]));
        st.z = fmaxf(0.f, fmaf(acc[2][u], a1[u], b1v[u]));
        st.w = fmaxf(0.f, fmaf(acc[3][u], a1[u], b1v[u]));
        *(float4*)&x1n[(ct*2 + u)*32 + rt*4] = st;
      }
    }
    __syncthreads();
    {
      float acc[4][4] = {};
      for (int j = 0; j < 64; j++) {
        float4 av = *(const float4*)&x1n[j*32 + rt*4];
        float4 wvv = *(const float4*)&w2t[j*128 + ct*4];
        float aa[4] = {av.x, av.y, av.z, av.w};
        float ww[4] = {wvv.x, wvv.y, wvv.z, wvv.w};
#pragma unroll
      for (int r = 0; r < 4; r++)
#pragma unroll
        for (int u = 0; u < 4; u++) acc[r][u] = fmaf(aa[r], ww[u], acc[r][u]);
      }
      float mx[4], mn[4];
#pragma unroll
      for (int u = 0; u < 4; u++) {
        float x0 = acc[0][u], x1 = acc[1][u], x2 = acc[2][u], x3 = acc[3][u];
        s2[u] += ((x0 + x1) + (x2 + x3));
        q2[u] = fmaf(x0, x0, q2[u]); q2[u] = fmaf(x1, x1, q2[u]);
        q2[u] = fmaf(x2, x2, q2[u]); q2[u] = fmaf(x3, x3, q2[u]);
        mx[u] = fmaxf(fmaxf(x0, x1), fmaxf(x2, x3));
        mn[u] = fminf(fminf(x0, x1), fminf(x2, x3));
      }
#pragma unroll
      for (int off = 1; off < 8; off <<= 1) {
#pragma unroll
        for (int u = 0; u < 4; u++) {
          mx[u] = fmaxf(mx[u], __shfl_xor(mx[u], off, 64));
          mn[u] = fminf(mn[u], __shfl_xor(mn[u], off, 64));
        }
      }
      if (rt == 0) {
#pragma unroll
        for (int u = 0; u < 4; u++) {
          maxb[(size_t)gid*128 + ct*4 + u] = mx[u];
          minb[(size_t)gid*128 + ct*4 + u] = mn[u];
        }
      }
    }
  }
#pragma unroll
  for (int off = 1; off < 8; off <<= 1) {
#pragma unroll
    for (int u = 0; u < 4; u++) { s2[u] += __shfl_xor(s2[u], off, 64); q2[u] += __shfl_xor(q2[u], off, 64); }
  }
  if (rt == 0) {
#pragma unroll
    for (int u = 0; u < 4; u++) {
      size_t o = ((size_t)blockIdx.x * 128 + ct*4 + u) * 2;
      partials[o] = s2[u]; partials[o+1] = q2[u];
    }
  }
}

__global__ void k_fin(const float* __restrict__ partials, int nblk,
                      const float* __restrict__ g, const float* __restrict__ be,
                      float* __restrict__ statsF, int layer, int C) {
  int c = threadIdx.x;
  if (c >= C) return;
  float s = 0.f, q = 0.f;
  for (int k = 0; k < nblk; k++) {
    s += partials[((size_t)k * 128 + c) * 2];
    q += partials[((size_t)k * 128 + c) * 2 + 1];
  }
  const float inv = 1.0f / (float)NTOT;
  float mean = s * inv;
  float var = q * inv - mean * mean;
  float a = g[c] / sqrtf(var + 1e-5f);
  float bb = be[c] - mean * a;
  statsF[((size_t)layer * 128 + c) * 2]     = a;
  statsF[((size_t)layer * 128 + c) * 2 + 1] = bb;
}

// ---------------------------------------------------------------------------
extern "C" void kernel_launch(void* const* d_in, const int* in_sizes, int n_in,
                              void* d_out, int out_size, void* d_ws, size_t ws_size,
                              hipStream_t stream) {
  (void)in_sizes; (void)n_in; (void)out_size;
  const float* xyz = (const float*)d_in[0];
  const float* pts = (const float*)d_in[1];
  const float* w0  = (const float*)d_in[2];
  const float* g0  = (const float*)d_in[4];
  const float* be0 = (const float*)d_in[5];
  const float* w1  = (const float*)d_in[6];
  const float* g1  = (const float*)d_in[8];
  const float* be1 = (const float*)d_in[9];
  const float* w2  = (const float*)d_in[10];
  const float* g2  = (const float*)d_in[12];
  const float* be2 = (const float*)d_in[13];

  float* out = (float*)d_out;
  float* newxyz = out;
  float* pooled = out + (size_t)NB*NS*3;

  float* ws = (float*)d_ws;
  const size_t needA = ((size_t)65536 + 33554432 + 131072 + 768
                        + 2097152 + 2097152 + 64) * 4;
  if (ws_size >= needA) {
    // ===== PATH A: streamed x0, 4 dispatches =====
    float* pp     = ws;                                  // 65536
    float* x0     = ws + 65536;                          // 33,554,432
    float* part   = x0 + 33554432;                       // 131072
    float* statsF = part + 131072;                       // 768
    float* maxb   = statsF + 768;                        // 2,097,152
    float* minb   = maxb + 2097152;                      // 2,097,152
    unsigned* sync = (unsigned*)(minb + 2097152);        // prog[8], ctr0..2

    hipMemsetAsync(sync, 0, 64, stream);
    k_stage1A<<<256, 256, 0, stream>>>(xyz, pts, w0, g0, be0,
                                       newxyz, pp, x0, part, statsF, sync);
    k_l1x<<<512, 256, 0, stream>>>(x0, w1, g1, be1, statsF, part, sync);
    k_l2x<<<256, 256, 0, stream>>>(x0, w1, w2, g2, be2, statsF, part,
                                   maxb, minb, sync);
    k_pool<<<8192, 256, 0, stream>>>(maxb, minb, statsF, pooled);
  } else {
    // ===== PATH B: proven R10 pipeline =====
    float* pp     = ws;                                 // 65536
    int*   idx    = (int*)(ws + 65536);                 // 524288 ints
    float* part   = ws + 65536 + 524288;                // 131072 reserved
    float* statsF = part + 131072;                      // 768
    float* maxb   = statsF + 768;                       // 2097152
    float* minb   = maxb + 2097152;                     // 2097152
    unsigned* prog = (unsigned*)(minb + 2097152);       // 8 progress + flag
    unsigned* flag = prog + 8;

    k_stage1<<<256, 256, 0, stream>>>(xyz, pts, w0, newxyz, pp, idx, part, prog, flag);
    k_fin<<<1, 128, 0, stream>>>(part, NCONS, g0, be0, statsF, 0, 64);
    k_l1stats<<<512, 256, 0, stream>>>(xyz, pts, newxyz, idx, w0, w1, statsF, part);
    k_fin<<<1, 128, 0, stream>>>(part, 512, g1, be1, statsF, 1, 64);
    k_l2<<<256, 256, 0, stream>>>(xyz, pts, newxyz, idx, w0, w1, w2, statsF, part, maxb, minb);
    k_fin<<<1, 128, 0, stream>>>(part, 256, g2, be2, statsF, 2, 128);
    k_pool<<<8192, 256, 0, stream>>>(maxb, minb, statsF, pooled);
  }
}

// Round 12
// 2613.774 us; speedup vs baseline: 1.5580x; 1.1116x over previous
//
#include <hip/hip_runtime.h>

#define NPTS 8192
#define NB 8
#define NS 2048
#define NK 32
#define C0 67
#define NTOT (NB*NS*NK)   // 524288 rows
#define NCONS 248
#define MAGIC 0xC0FFEE01u

typedef __attribute__((ext_vector_type(2))) float f32x2;

// ---- DPP wave64 reduce helpers ---------------------------------------------
template <int CTRL, int ROWM>
__device__ __forceinline__ float dpp_fmax_step(float x) {
  int yi = __builtin_amdgcn_update_dpp(__float_as_int(x), __float_as_int(x),
                                       CTRL, ROWM, 0xf, false);
  return fmaxf(x, __int_as_float(yi));
}
template <int CTRL, int ROWM>
__device__ __forceinline__ unsigned dpp_umin_step(unsigned x) {
  unsigned y = (unsigned)__builtin_amdgcn_update_dpp((int)x, (int)x,
                                                     CTRL, ROWM, 0xf, false);
  return (y < x) ? y : x;
}
__device__ __forceinline__ float wave_max_f32(float v) {
  v = dpp_fmax_step<0x111, 0xf>(v);
  v = dpp_fmax_step<0x112, 0xf>(v);
  v = dpp_fmax_step<0x114, 0xf>(v);
  v = dpp_fmax_step<0x118, 0xf>(v);
  v = dpp_fmax_step<0x142, 0xa>(v);
  v = dpp_fmax_step<0x143, 0xc>(v);
  return v;
}
__device__ __forceinline__ unsigned wave_min_u32(unsigned v) {
  v = dpp_umin_step<0x111, 0xf>(v);
  v = dpp_umin_step<0x112, 0xf>(v);
  v = dpp_umin_step<0x114, 0xf>(v);
  v = dpp_umin_step<0x118, 0xf>(v);
  v = dpp_umin_step<0x142, 0xa>(v);
  v = dpp_umin_step<0x143, 0xc>(v);
  return v;
}

// ===========================================================================
// ============================ PATH A (streamed x0) =========================
// ===========================================================================
union SMemA {
  struct {
    float sx[NPTS], sy[NPTS], sz[NPTS];
    float snx[NS], sny[NS], snz[NS];
    uint2 slotVN[2][4];
  } fps;
  struct {
    float w0t[C0*64];
    float feat[C0*32];
    int   bq[4][32];
    int   bqc[4];
    int   s_idx[32];
    float s_c[3];
  } con;
};

// Stage1: FPS producers (blocks 0..7) + consumers (8..255): BQ + gather +
// L0 GEMM -> stream raw x0 to global + stats0; last consumer computes statsF0.
// Producer inner loop uses PACKED f32 (v_pk_*): bit-exact rn per component,
// contract(off) so no fma fusion -> identical FPS decisions.
__global__ __launch_bounds__(256, 1) void k_stage1A(
    const float* __restrict__ xyz, const float* __restrict__ pts,
    const float* __restrict__ w0, const float* __restrict__ g0,
    const float* __restrict__ be0,
    float* __restrict__ newxyz, float* __restrict__ pp,
    float* __restrict__ x0, float* __restrict__ part,
    float* __restrict__ statsF, unsigned* __restrict__ sync) {
  __shared__ __align__(16) SMemA sm;
  __shared__ int s_last;
  const int tid = threadIdx.x;
  unsigned* prog = sync;           // [0..7] zeroed by memset
  unsigned* ctr0 = sync + 8;

  if (blockIdx.x < NB) {
    // ===================== PRODUCER: FPS =====================
    const int b = blockIdx.x;
    const int wv = tid >> 6, lane = tid & 63;
    const float* Xb = xyz + (size_t)b * NPTS * 3;
    f32x2 px2[16], py2[16], pz2[16], mind2[16];
#pragma unroll
    for (int i = 0; i < 16; i++) {
      int n0 = ((2*i) << 8) | tid;
      int n1 = ((2*i+1) << 8) | tid;
      float ax = Xb[n0*3+0], ay = Xb[n0*3+1], az = Xb[n0*3+2];
      float bx2 = Xb[n1*3+0], by2 = Xb[n1*3+1], bz2 = Xb[n1*3+2];
      px2[i].x = ax;  px2[i].y = bx2;
      py2[i].x = ay;  py2[i].y = by2;
      pz2[i].x = az;  pz2[i].y = bz2;
      sm.fps.sx[n0]=ax;  sm.fps.sy[n0]=ay;  sm.fps.sz[n0]=az;
      sm.fps.sx[n1]=bx2; sm.fps.sy[n1]=by2; sm.fps.sz[n1]=bz2;
      pp[b*NPTS + n0] = __fadd_rn(__fadd_rn(__fmul_rn(ax,ax), __fmul_rn(ay,ay)), __fmul_rn(az,az));
      pp[b*NPTS + n1] = __fadd_rn(__fadd_rn(__fmul_rn(bx2,bx2), __fmul_rn(by2,by2)), __fmul_rn(bz2,bz2));
      mind2[i].x = 1e10f; mind2[i].y = 1e10f;
    }
    __syncthreads();
    float lx = sm.fps.sx[0], ly = sm.fps.sy[0], lz = sm.fps.sz[0];
    if (tid == 0) { sm.fps.snx[0]=lx; sm.fps.sny[0]=ly; sm.fps.snz[0]=lz; }
    for (int s = 1; s < NS; s++) {
#pragma clang fp contract(off)
      f32x2 lxx = {lx, lx}, lyy = {ly, ly}, lzz = {lz, lz};
      f32x2 m16[16];
#pragma unroll
      for (int i = 0; i < 16; i++) {
        f32x2 dx = px2[i] - lxx;
        f32x2 dy = py2[i] - lyy;
        f32x2 dz = pz2[i] - lzz;
        f32x2 d  = (dx*dx + dy*dy) + dz*dz;   // rn mul/add, no fma (contract off)
        f32x2 m;
        m.x = fminf(mind2[i].x, d.x);
        m.y = fminf(mind2[i].y, d.y);
        mind2[i] = m;
        m16[i] = m;
      }
      // balanced max tree (exact op -> association-order free)
#pragma unroll
      for (int st = 8; st >= 1; st >>= 1)
#pragma unroll
        for (int i = 0; i < st; i++) {
          m16[i].x = fmaxf(m16[i].x, m16[i+st].x);
          m16[i].y = fmaxf(m16[i].y, m16[i+st].y);
        }
      float v = fmaxf(m16[0].x, m16[0].y);
      float vr = wave_max_f32(v);
      float wmax = __int_as_float(__builtin_amdgcn_readlane(__float_as_int(vr), 63));
      // first k (0..31) with mind==v ; k=2i -> .x, k=2i+1 -> .y
      int kk = 31;
#pragma unroll
      for (int i = 15; i >= 0; i--) {
        kk = (mind2[i].y == v) ? (2*i+1) : kk;
        kk = (mind2[i].x == v) ? (2*i)   : kk;
      }
      unsigned ncand = (v == wmax) ? (unsigned)((kk << 8) | tid) : 0xffffffffu;
      unsigned nr = wave_min_u32(ncand);
      int buf = s & 1;
      if (lane == 63) sm.fps.slotVN[buf][wv] = make_uint2(__float_as_uint(vr), nr);
      __syncthreads();
      uint4 s01 = *(const uint4*)&sm.fps.slotVN[buf][0];
      uint4 s23 = *(const uint4*)&sm.fps.slotVN[buf][2];
      unsigned bx = s01.x, by = s01.y;
      if (s01.z > bx || (s01.z == bx && s01.w < by)) { bx = s01.z; by = s01.w; }
      if (s23.x > bx || (s23.x == bx && s23.y < by)) { bx = s23.x; by = s23.y; }
      if (s23.z > bx || (s23.z == bx && s23.w < by)) { bx = s23.z; by = s23.w; }
      int n = (int)by;
      lx = sm.fps.sx[n]; ly = sm.fps.sy[n]; lz = sm.fps.sz[n];
      if (tid == 0) { sm.fps.snx[s]=lx; sm.fps.sny[s]=ly; sm.fps.snz[s]=lz; }
      if ((s & 63) == 63) {
        __syncthreads();
        int cs = s - 63;
        if (tid < 192) {
          int e = cs + tid / 3, comp = tid - (tid / 3) * 3;
          float vvv = (comp == 0) ? sm.fps.snx[e] : ((comp == 1) ? sm.fps.sny[e] : sm.fps.snz[e]);
          newxyz[((size_t)b*NS + cs)*3 + tid] = vvv;
        }
        __syncthreads();
        if (tid == 0) {
          __threadfence();
          __hip_atomic_store(&prog[b], (unsigned)(s + 1), __ATOMIC_RELEASE, __HIP_MEMORY_SCOPE_AGENT);
        }
      }
    }
  } else {
    // ===================== CONSUMER: BQ + L0 -> x0 stream =====================
    const int cb = blockIdx.x - NB;          // 0..247
    const int wv = tid >> 6, lane = tid & 63;
    float* w0t = sm.con.w0t;
    float* feat = sm.con.feat;
    for (int t = tid; t < C0*64; t += 256) { int j = t >> 6, c = t & 63; w0t[t] = w0[c*C0 + j]; }
    int rt = tid & 7, ct = tid >> 3;
    float s0[2] = {0,0}, q0[2] = {0,0};
    for (int it = 0; it <= 66; it++) {
      int e = cb + NCONS * it;
      if (e >= NB*NS) break;
      int s = e >> 3, b = e & 7;
      size_t row = (size_t)b * NS + s;
      if (tid == 0) {
        while ((int)__hip_atomic_load(&prog[b], __ATOMIC_ACQUIRE, __HIP_MEMORY_SCOPE_AGENT) <= s)
          __builtin_amdgcn_s_sleep(32);
        __threadfence();
      }
      __syncthreads();
      const float* c3 = newxyz + row * 3;
      float cx = c3[0], cy = c3[1], cz = c3[2];
      float qq = __fadd_rn(__fadd_rn(__fmul_rn(cx,cx), __fmul_rn(cy,cy)), __fmul_rn(cz,cz));
      const float* Xb = xyz + (size_t)b * NPTS * 3;
      const float* Pb = pp + b * NPTS;
      int cnt = 0;
      int base = wv << 11;
      for (int j0 = base; j0 < base + 2048; j0 += 64) {
        int n = j0 + lane;
        float x = Xb[n*3+0], y = Xb[n*3+1], z = Xb[n*3+2];
        float dot = __fadd_rn(__fadd_rn(__fmul_rn(cx,x), __fmul_rn(cy,y)), __fmul_rn(cz,z));
        float d2 = __fsub_rn(__fadd_rn(qq, Pb[n]), __fmul_rn(2.0f, dot));
        bool in = (d2 <= 0.0625f);
        unsigned long long bal = __ballot(in);
        if (in) {
          int pos = cnt + (int)__popcll(bal & ((1ull << lane) - 1ull));
          if (pos < NK) sm.con.bq[wv][pos] = n;
        }
        cnt += (int)__popcll(bal);
        if (cnt >= NK) break;
      }
      if (lane == 0) sm.con.bqc[wv] = (cnt < NK) ? cnt : NK;
      __syncthreads();
      if (tid < NK) {
        int l0 = sm.con.bqc[0], l1 = sm.con.bqc[1], l2 = sm.con.bqc[2], l3 = sm.con.bqc[3];
        int t1 = l0 + l1, t2 = t1 + l2, t3 = t2 + l3;
        int j = tid, v;
        if (j < l0)      v = sm.con.bq[0][j];
        else if (j < t1) v = sm.con.bq[1][j - l0];
        else if (j < t2) v = sm.con.bq[2][j - t1];
        else if (j < t3) v = sm.con.bq[3][j - t2];
        else {
          v = (l0 > 0) ? sm.con.bq[0][0] : (l1 > 0) ? sm.con.bq[1][0]
            : (l2 > 0) ? sm.con.bq[2][0] : (l3 > 0) ? sm.con.bq[3][0] : 0;
        }
        sm.con.s_idx[j] = v;
      }
      if (tid >= 32 && tid < 35) sm.con.s_c[tid - 32] = c3[tid - 32];
      __syncthreads();
      if (tid < 32) {
        const float* p = &xyz[((size_t)b*NPTS + sm.con.s_idx[tid])*3];
        feat[0*32+tid] = p[0] - sm.con.s_c[0];
        feat[1*32+tid] = p[1] - sm.con.s_c[1];
        feat[2*32+tid] = p[2] - sm.con.s_c[2];
      }
      {
        int r_ = tid & 31, cq_ = tid >> 5;
        const float* pr = &pts[((size_t)b*NPTS + sm.con.s_idx[r_])*64 + cq_*8];
        float4 A_ = *(const float4*)pr;
        float4 B_ = *(const float4*)(pr + 4);
        feat[(3+cq_*8+0)*32 + r_] = A_.x;
        feat[(3+cq_*8+1)*32 + r_] = A_.y;
        feat[(3+cq_*8+2)*32 + r_] = A_.z;
        feat[(3+cq_*8+3)*32 + r_] = A_.w;
        feat[(3+cq_*8+4)*32 + r_] = B_.x;
        feat[(3+cq_*8+5)*32 + r_] = B_.y;
        feat[(3+cq_*8+6)*32 + r_] = B_.z;
        feat[(3+cq_*8+7)*32 + r_] = B_.w;
      }
      __syncthreads();
      float acc[4][2] = {};
      for (int j = 0; j < C0; j++) {
        float4 av = *(const float4*)&feat[j*32 + rt*4];
        float2 wvv = *(const float2*)&w0t[j*64 + ct*2];
        float aa[4] = {av.x, av.y, av.z, av.w};
#pragma unroll
        for (int r = 0; r < 4; r++) {
          acc[r][0] = fmaf(aa[r], wvv.x, acc[r][0]);
          acc[r][1] = fmaf(aa[r], wvv.y, acc[r][1]);
        }
      }
      // stream raw x0 (pre-BN) + accumulate stats
      float* dst = x0 + row * 2048;
#pragma unroll
      for (int r = 0; r < 4; r++)
#pragma unroll
        for (int u = 0; u < 2; u++) {
          float x = acc[r][u];
          dst[(rt*4+r)*64 + ct*2+u] = x;
          s0[u] += x; q0[u] = fmaf(x, x, q0[u]);
        }
      __syncthreads();
    }
#pragma unroll
    for (int off = 1; off < 8; off <<= 1) {
#pragma unroll
      for (int u = 0; u < 2; u++) { s0[u] += __shfl_xor(s0[u], off, 64); q0[u] += __shfl_xor(q0[u], off, 64); }
    }
    if (rt == 0) {
#pragma unroll
      for (int u = 0; u < 2; u++) {
        size_t o = ((size_t)cb * 128 + ct*2 + u) * 2;
        part[o] = s0[u]; part[o+1] = q0[u];
      }
    }
    // ---- fused fin0: last consumer block reduces partials -> statsF0 ----
    __threadfence();
    if (tid == 0) {
      unsigned old = __hip_atomic_fetch_add(ctr0, 1u, __ATOMIC_ACQ_REL, __HIP_MEMORY_SCOPE_AGENT);
      s_last = (old == NCONS - 1);
    }
    __syncthreads();
    if (s_last) {
      __threadfence();
      if (tid < 64) {
        float s = 0.f, q = 0.f;
        for (int k = 0; k < NCONS; k++) {
          s += part[((size_t)k * 128 + tid) * 2];
          q += part[((size_t)k * 128 + tid) * 2 + 1];
        }
        const float inv = 1.0f / (float)NTOT;
        float mean = s * inv;
        float var = q * inv - mean * mean;
        float a = g0[tid] / sqrtf(var + 1e-5f);
        float bb = be0[tid] - mean * a;
        statsF[tid*2] = a; statsF[tid*2 + 1] = bb;
      }
    }
  }
}

// L1 pass (path A): read x0, BN0+ReLU, L1 GEMM; store raw x1 IN PLACE over x0
// (group-exclusive ownership; x0 dead afterwards); stats1; fused fin1.
__global__ __launch_bounds__(256) void k_l1x(
    float* __restrict__ x0, const float* __restrict__ w1,
    const float* __restrict__ g1, const float* __restrict__ be1,
    float* __restrict__ statsF, float* __restrict__ part,
    unsigned* __restrict__ sync) {
  __shared__ __align__(16) float w1t[64*64];
  __shared__ __align__(16) float x0n[64*32];
  __shared__ float sF[128];
  __shared__ int s_last;
  unsigned* ctr1 = sync + 9;
  int tid = threadIdx.x;
  for (int t = tid; t < 64*64; t += 256) { int j = t >> 6, c = t & 63; w1t[t] = w1[c*64 + j]; }
  if (tid < 64) { sF[tid] = statsF[tid*2]; sF[64+tid] = statsF[tid*2+1]; }
  int rt = tid & 7, ct = tid >> 3;
  float s1[2] = {0,0}, q1[2] = {0,0};
  for (int g = 0; g < 32; g++) {
    size_t gid = (size_t)blockIdx.x * 32 + g;
    __syncthreads();   // protect x0n reuse
    float* src = x0 + gid * 2048;
#pragma unroll
    for (int i = 0; i < 2; i++) {
      int local = tid*8 + i*4;
      float4 v = *(const float4*)(src + local);
      int row = local >> 6, col = local & 63;
      x0n[(col+0)*32+row] = fmaxf(0.f, fmaf(v.x, sF[col+0], sF[64+col+0]));
      x0n[(col+1)*32+row] = fmaxf(0.f, fmaf(v.y, sF[col+1], sF[64+col+1]));
      x0n[(col+2)*32+row] = fmaxf(0.f, fmaf(v.z, sF[col+2], sF[64+col+2]));
      x0n[(col+3)*32+row] = fmaxf(0.f, fmaf(v.w, sF[col+3], sF[64+col+3]));
    }
    __syncthreads();
    float acc[4][2] = {};
    for (int j = 0; j < 64; j++) {
      float4 av = *(const float4*)&x0n[j*32 + rt*4];
      float2 wv = *(const float2*)&w1t[j*64 + ct*2];
      float aa[4] = {av.x, av.y, av.z, av.w};
#pragma unroll
      for (int r = 0; r < 4; r++) {
        acc[r][0] = fmaf(aa[r], wv.x, acc[r][0]);
        acc[r][1] = fmaf(aa[r], wv.y, acc[r][1]);
      }
    }
    // store raw x1 in place (consumed only by k_l2x) + stats
#pragma unroll
    for (int r = 0; r < 4; r++)
#pragma unroll
      for (int u = 0; u < 2; u++) {
        float x = acc[r][u];
        src[(rt*4+r)*64 + ct*2+u] = x;
        s1[u] += x; q1[u] = fmaf(x, x, q1[u]);
      }
  }
#pragma unroll
  for (int off = 1; off < 8; off <<= 1) {
#pragma unroll
    for (int u = 0; u < 2; u++) { s1[u] += __shfl_xor(s1[u], off, 64); q1[u] += __shfl_xor(q1[u], off, 64); }
  }
  if (rt == 0) {
#pragma unroll
    for (int u = 0; u < 2; u++) {
      size_t o = ((size_t)blockIdx.x * 128 + ct*2 + u) * 2;
      part[o] = s1[u]; part[o+1] = q1[u];
    }
  }
  __threadfence();
  if (tid == 0) {
    unsigned old = __hip_atomic_fetch_add(ctr1, 1u, __ATOMIC_ACQ_REL, __HIP_MEMORY_SCOPE_AGENT);
    s_last = (old == 511);
  }
  __syncthreads();
  if (s_last) {
    __threadfence();
    if (tid < 64) {
      float s = 0.f, q = 0.f;
      for (int k = 0; k < 512; k++) {
        s += part[((size_t)k * 128 + tid) * 2];
        q += part[((size_t)k * 128 + tid) * 2 + 1];
      }
      const float inv = 1.0f / (float)NTOT;
      float mean = s * inv;
      float var = q * inv - mean * mean;
      float a = g1[tid] / sqrtf(var + 1e-5f);
      float bb = be1[tid] - mean * a;
      statsF[(128 + tid)*2] = a; statsF[(128 + tid)*2 + 1] = bb;
    }
  }
}

// L2 pass (path A, SLIM): read raw x1 (in x0 buffer), BN1+ReLU, L2 GEMM only;
// stats2 + per-group max/min; fused fin2.
__global__ __launch_bounds__(256) void k_l2x(
    const float* __restrict__ x1, const float* __restrict__ w2,
    const float* __restrict__ g2, const float* __restrict__ be2,
    float* __restrict__ statsF, float* __restrict__ part,
    float* __restrict__ maxb, float* __restrict__ minb,
    unsigned* __restrict__ sync) {
  __shared__ __align__(16) float w2t[64*128];
  __shared__ __align__(16) float x1n[64*32];
  __shared__ float sF[128];
  __shared__ int s_last;
  unsigned* ctr2 = sync + 10;
  int tid = threadIdx.x;
  for (int t = tid; t < 64*128; t += 256) { int j = t >> 7, c = t & 127; w2t[t] = w2[c*64 + j]; }
  if (tid < 64) { sF[tid] = statsF[(128+tid)*2]; sF[64+tid] = statsF[(128+tid)*2+1]; }
  int rt = tid & 7, ct = tid >> 3;
  float s2[4] = {0,0,0,0}, q2[4] = {0,0,0,0};
  for (int g = 0; g < 64; g++) {
    size_t gid = (size_t)blockIdx.x * 64 + g;
    __syncthreads();   // protect x1n reuse; covers sF/w2t on first iter
    const float* src = x1 + gid * 2048;
#pragma unroll
    for (int i = 0; i < 2; i++) {
      int local = tid*8 + i*4;
      float4 v = *(const float4*)(src + local);
      int row = local >> 6, col = local & 63;
      x1n[(col+0)*32+row] = fmaxf(0.f, fmaf(v.x, sF[col+0], sF[64+col+0]));
      x1n[(col+1)*32+row] = fmaxf(0.f, fmaf(v.y, sF[col+1], sF[64+col+1]));
      x1n[(col+2)*32+row] = fmaxf(0.f, fmaf(v.z, sF[col+2], sF[64+col+2]));
      x1n[(col+3)*32+row] = fmaxf(0.f, fmaf(v.w, sF[col+3], sF[64+col+3]));
    }
    __syncthreads();
    float acc[4][4] = {};
    for (int j = 0; j < 64; j++) {
      float4 av = *(const float4*)&x1n[j*32 + rt*4];
      float4 wvv = *(const float4*)&w2t[j*128 + ct*4];
      float aa[4] = {av.x, av.y, av.z, av.w};
      float ww[4] = {wvv.x, wvv.y, wvv.z, wvv.w};
#pragma unroll
      for (int r = 0; r < 4; r++)
#pragma unroll
        for (int u = 0; u < 4; u++) acc[r][u] = fmaf(aa[r], ww[u], acc[r][u]);
    }
    float mx[4], mn[4];
#pragma unroll
    for (int u = 0; u < 4; u++) {
      float x0v = acc[0][u], x1v = acc[1][u], x2v = acc[2][u], x3v = acc[3][u];
      s2[u] += ((x0v + x1v) + (x2v + x3v));
      q2[u] = fmaf(x0v, x0v, q2[u]); q2[u] = fmaf(x1v, x1v, q2[u]);
      q2[u] = fmaf(x2v, x2v, q2[u]); q2[u] = fmaf(x3v, x3v, q2[u]);
      mx[u] = fmaxf(fmaxf(x0v, x1v), fmaxf(x2v, x3v));
      mn[u] = fminf(fminf(x0v, x1v), fminf(x2v, x3v));
    }
#pragma unroll
    for (int off = 1; off < 8; off <<= 1) {
#pragma unroll
      for (int u = 0; u < 4; u++) {
        mx[u] = fmaxf(mx[u], __shfl_xor(mx[u], off, 64));
        mn[u] = fminf(mn[u], __shfl_xor(mn[u], off, 64));
      }
    }
    if (rt == 0) {
#pragma unroll
      for (int u = 0; u < 4; u++) {
        maxb[gid*128 + ct*4 + u] = mx[u];
        minb[gid*128 + ct*4 + u] = mn[u];
      }
    }
  }
#pragma unroll
  for (int off = 1; off < 8; off <<= 1) {
#pragma unroll
    for (int u = 0; u < 4; u++) { s2[u] += __shfl_xor(s2[u], off, 64); q2[u] += __shfl_xor(q2[u], off, 64); }
  }
  if (rt == 0) {
#pragma unroll
    for (int u = 0; u < 4; u++) {
      size_t o = ((size_t)blockIdx.x * 128 + ct*4 + u) * 2;
      part[o] = s2[u]; part[o+1] = q2[u];
    }
  }
  __threadfence();
  if (tid == 0) {
    unsigned old = __hip_atomic_fetch_add(ctr2, 1u, __ATOMIC_ACQ_REL, __HIP_MEMORY_SCOPE_AGENT);
    s_last = (old == 255);
  }
  __syncthreads();
  if (s_last) {
    __threadfence();
    if (tid < 128) {
      float s = 0.f, q = 0.f;
      for (int k = 0; k < 256; k++) {
        s += part[((size_t)k * 128 + tid) * 2];
        q += part[((size_t)k * 128 + tid) * 2 + 1];
      }
      const float inv = 1.0f / (float)NTOT;
      float mean = s * inv;
      float var = q * inv - mean * mean;
      float a = g2[tid] / sqrtf(var + 1e-5f);
      float bb = be2[tid] - mean * a;
      statsF[(256 + tid)*2] = a; statsF[(256 + tid)*2 + 1] = bb;
    }
  }
}

// Pool epilogue: pooled = relu(a*X + beta), X = a>=0 ? max : min.
__global__ __launch_bounds__(256) void k_pool(const float* __restrict__ maxb,
                                              const float* __restrict__ minb,
                                              const float* __restrict__ statsF,
                                              float* __restrict__ outp) {
  int t = blockIdx.x * 256 + threadIdx.x;
  int c = t & 127;
  float a  = statsF[(2*128 + c)*2];
  float bb = statsF[(2*128 + c)*2 + 1];
  float X = (a >= 0.f) ? maxb[t] : minb[t];
  outp[t] = fmaxf(0.f, fmaf(a, X, bb));
}

// ---------------------------------------------------------------------------
extern "C" void kernel_launch(void* const* d_in, const int* in_sizes, int n_in,
                              void* d_out, int out_size, void* d_ws, size_t ws_size,
                              hipStream_t stream) {
  (void)in_sizes; (void)n_in; (void)out_size; (void)ws_size;
  const float* xyz = (const float*)d_in[0];
  const float* pts = (const float*)d_in[1];
  const float* w0  = (const float*)d_in[2];
  const float* g0  = (const float*)d_in[4];
  const float* be0 = (const float*)d_in[5];
  const float* w1  = (const float*)d_in[6];
  const float* g1  = (const float*)d_in[8];
  const float* be1 = (const float*)d_in[9];
  const float* w2  = (const float*)d_in[10];
  const float* g2  = (const float*)d_in[12];
  const float* be2 = (const float*)d_in[13];

  float* out = (float*)d_out;
  float* newxyz = out;
  float* pooled = out + (size_t)NB*NS*3;

  float* ws = (float*)d_ws;
  // Path A layout (proven to fit in R11): pp | x0 | part | statsF | maxb | minb | sync
  float* pp     = ws;                                  // 65536
  float* x0     = ws + 65536;                          // 33,554,432 (x1 in place later)
  float* part   = x0 + 33554432;                       // 131072
  float* statsF = part + 131072;                       // 768
  float* maxb   = statsF + 768;                        // 2,097,152
  float* minb   = maxb + 2097152;                      // 2,097,152
  unsigned* sync = (unsigned*)(minb + 2097152);        // prog[8], ctr0..2

  hipMemsetAsync(sync, 0, 64, stream);
  k_stage1A<<<256, 256, 0, stream>>>(xyz, pts, w0, g0, be0,
                                     newxyz, pp, x0, part, statsF, sync);
  k_l1x<<<512, 256, 0, stream>>>(x0, w1, g1, be1, statsF, part, sync);
  k_l2x<<<256, 256, 0, stream>>>(x0, w2, g2, be2, statsF, part,
                                 maxb, minb, sync);
  k_pool<<<8192, 256, 0, stream>>>(maxb, minb, statsF, pooled);
}